// Round 1
// baseline (1586.115 us; speedup 1.0000x reference)
//
#include <hip/hip_runtime.h>
#include <math.h>

#define NN 50000
#define EE 800000
#define ET (EE + NN)   // 850000 edges incl. self-loops
#define C  64

// ---------------------------------------------------------------------------
// Shared GEMM microkernel: out[m][o] = sum_k AT[k*64+m] * WT[k*64+o]
// AT is A transposed (k-major), WT is W transposed (k-major) so that
// (A @ W.T)[m][o] = sum_k A[m][k]*W[o][k] = sum_k AT[k][m]*WT[k][o].
// 256 threads: mg = tid&15 (m0=4*mg), og = tid>>4 (o0=4*og); 4x4 acc/thread.
// float4 LDS reads are conflict-free: per 8-lane phase the 16B reads tile all
// 32 banks exactly (A operand), W operand is broadcast within a phase.
// ---------------------------------------------------------------------------
__device__ __forceinline__ void gemm64(const float* __restrict__ AT,
                                       const float* __restrict__ WT,
                                       int m0, int o0, float acc[4][4]) {
#pragma unroll 8
  for (int k = 0; k < 64; ++k) {
    const float4 a = *(const float4*)(AT + k * 64 + m0);
    const float4 w = *(const float4*)(WT + k * 64 + o0);
    const float av[4] = {a.x, a.y, a.z, a.w};
    const float wv[4] = {w.x, w.y, w.z, w.w};
#pragma unroll
    for (int i = 0; i < 4; ++i)
#pragma unroll
      for (int j = 0; j < 4; ++j) acc[i][j] = fmaf(av[i], wv[j], acc[i][j]);
  }
}

// Load 64x64 row-major weight W[o][k] from global, store transposed WT[k][o].
__device__ __forceinline__ void load_wT(float* __restrict__ dst,
                                        const float* __restrict__ W, int tid) {
  const int o = tid >> 2;
  const int kc = (tid & 3) * 16;
  const float4* src = (const float4*)(W + o * 64 + kc);
#pragma unroll
  for (int u = 0; u < 4; ++u) {
    const float4 wv = src[u];
    const int kb = kc + 4 * u;
    dst[(kb + 0) * 64 + o] = wv.x;
    dst[(kb + 1) * 64 + o] = wv.y;
    dst[(kb + 2) * 64 + o] = wv.z;
    dst[(kb + 3) * 64 + o] = wv.w;
  }
}

// ---------------------------------------------------------------------------
// Kernel A: h = relu(x@W_in.T + b_in); v = h@W_lin.T; k = h@W_src.T; q = h@W_dst.T
// ---------------------------------------------------------------------------
__global__ __launch_bounds__(256, 3) void node_proj(
    const float* __restrict__ x, const float* __restrict__ W_in,
    const float* __restrict__ b_in, const float* __restrict__ W_lin,
    const float* __restrict__ W_src, const float* __restrict__ W_dst,
    float* __restrict__ v, float* __restrict__ kk, float* __restrict__ q) {
  __shared__ __align__(16) float bufX[64 * 64];  // xT [k][n]
  __shared__ __align__(16) float bufH[64 * 64];  // hT [k][n]
  __shared__ __align__(16) float wbuf[64 * 64];  // WT [k][o]
  __shared__ __align__(16) float bias[64];

  const int tid = threadIdx.x;
  const int nb = blockIdx.x * 64;
  const int m0 = (tid & 15) * 4;
  const int o0 = (tid >> 4) * 4;

  // stage xT
  {
    const int n = tid >> 2;
    const int kc = (tid & 3) * 16;
    const int gn = nb + n;
#pragma unroll
    for (int u = 0; u < 4; ++u) {
      float4 xv = make_float4(0.f, 0.f, 0.f, 0.f);
      if (gn < NN) xv = *(const float4*)(x + (size_t)gn * 64 + kc + 4 * u);
      const int kb = kc + 4 * u;
      bufX[(kb + 0) * 64 + n] = xv.x;
      bufX[(kb + 1) * 64 + n] = xv.y;
      bufX[(kb + 2) * 64 + n] = xv.z;
      bufX[(kb + 3) * 64 + n] = xv.w;
    }
  }
  load_wT(wbuf, W_in, tid);
  if (tid < 64) bias[tid] = b_in[tid];
  __syncthreads();

  float acc[4][4] = {};
  gemm64(bufX, wbuf, m0, o0, acc);
#pragma unroll
  for (int i = 0; i < 4; ++i)
#pragma unroll
    for (int j = 0; j < 4; ++j) {
      const float h = fmaxf(acc[i][j] + bias[o0 + j], 0.f);
      bufH[(o0 + j) * 64 + (m0 + i)] = h;  // hT [k][n]
    }
  __syncthreads();

  const float* Ws[3] = {W_lin, W_src, W_dst};
  float* outs[3] = {v, kk, q};
#pragma unroll 1
  for (int p = 0; p < 3; ++p) {
    load_wT(wbuf, Ws[p], tid);
    __syncthreads();
    float a2[4][4] = {};
    gemm64(bufH, wbuf, m0, o0, a2);
#pragma unroll
    for (int i = 0; i < 4; ++i) {
      const int gn = nb + m0 + i;
      if (gn < NN) {
        const float4 r = make_float4(a2[i][0], a2[i][1], a2[i][2], a2[i][3]);
        *(float4*)(outs[p] + (size_t)gn * 64 + o0) = r;
      }
    }
    __syncthreads();  // protect wbuf before next overwrite
  }
}

// ---------------------------------------------------------------------------
// Kernel B: fused per-edge MLPs + exp + atomic num/den accumulation.
// 64 edges per block. LDS ~52KB -> 3 blocks/CU.
// ---------------------------------------------------------------------------
__global__ __launch_bounds__(256, 3) void edge_pass(
    const int* __restrict__ ei, const float* __restrict__ pos,
    const float* __restrict__ vv, const float* __restrict__ kk,
    const float* __restrict__ qq, const float* __restrict__ att_w1,
    const float* __restrict__ att_b1, const float* __restrict__ att_w2,
    const float* __restrict__ att_b2, const float* __restrict__ pos_w1,
    const float* __restrict__ pos_b1, const float* __restrict__ pos_w2,
    const float* __restrict__ pos_b2, float* __restrict__ num,
    float* __restrict__ den) {
  __shared__ __align__(16) float bufA[64 * 64];  // adT [j][e] -> later hpT [i][e]
  __shared__ __align__(16) float bufB[64 * 64];  // h1T [i][e]
  __shared__ __align__(16) float wbuf[64 * 64];  // w1T -> w2T -> posw2T
  __shared__ __align__(16) float posw1T[3 * 64]; // [j][i]
  __shared__ __align__(16) float dpT[3 * 64];    // [j][e]
  __shared__ __align__(16) float b1s[64], b2s[64], pb1s[64], pb2s[64];
  __shared__ int srcs[64], dsts[64];

  const int tid = threadIdx.x;
  const int eb = blockIdx.x * 64;
  const int m0 = (tid & 15) * 4;
  const int o0 = (tid >> 4) * 4;

  // ---- phase 0: gather ad = q[dst]-k[src], dp = pos[dst]-pos[src], weights
  {
    const int el = tid >> 2;
    const int e = eb + el;
    const int kc = (tid & 3) * 16;
    int s, d;
    if (e < EE) {
      s = ei[e];
      d = ei[EE + e];
    } else if (e < ET) {
      s = e - EE;
      d = s;
    } else {
      s = 0;
      d = 0;
    }
    if ((tid & 3) == 0) {
      srcs[el] = s;
      dsts[el] = d;
      dpT[0 * 64 + el] = pos[(size_t)d * 3 + 0] - pos[(size_t)s * 3 + 0];
      dpT[1 * 64 + el] = pos[(size_t)d * 3 + 1] - pos[(size_t)s * 3 + 1];
      dpT[2 * 64 + el] = pos[(size_t)d * 3 + 2] - pos[(size_t)s * 3 + 2];
    }
    const float4* qp = (const float4*)(qq + (size_t)d * 64 + kc);
    const float4* kp = (const float4*)(kk + (size_t)s * 64 + kc);
#pragma unroll
    for (int u = 0; u < 4; ++u) {
      const float4 a = qp[u];
      const float4 b = kp[u];
      const int kb = kc + 4 * u;
      bufA[(kb + 0) * 64 + el] = a.x - b.x;
      bufA[(kb + 1) * 64 + el] = a.y - b.y;
      bufA[(kb + 2) * 64 + el] = a.z - b.z;
      bufA[(kb + 3) * 64 + el] = a.w - b.w;
    }
  }
  if (tid < 64) {
    b1s[tid] = att_b1[tid];
    b2s[tid] = att_b2[tid];
    pb1s[tid] = pos_b1[tid];
    pb2s[tid] = pos_b2[tid];
    posw1T[0 * 64 + tid] = pos_w1[tid * 3 + 0];
    posw1T[1 * 64 + tid] = pos_w1[tid * 3 + 1];
    posw1T[2 * 64 + tid] = pos_w1[tid * 3 + 2];
  }
  load_wT(wbuf, att_w1, tid);
  __syncthreads();  // B0

  // ---- phase 1: h1 = relu(ad @ att_w1.T + b1) -> bufB
  {
    float acc[4][4] = {};
    gemm64(bufA, wbuf, m0, o0, acc);
#pragma unroll
    for (int i = 0; i < 4; ++i)
#pragma unroll
      for (int j = 0; j < 4; ++j) {
        const float h = fmaxf(acc[i][j] + b1s[o0 + j], 0.f);
        bufB[(o0 + j) * 64 + (m0 + i)] = h;
      }
  }
  __syncthreads();  // B1: bufA & wbuf free

  load_wT(wbuf, att_w2, tid);
  // ---- phase 2: hp = relu(dp @ pos_w1.T + pb1) (k=3) -> bufA
  {
    float acc[4][4] = {};
#pragma unroll
    for (int k = 0; k < 3; ++k) {
      const float4 a = *(const float4*)(dpT + k * 64 + m0);
      const float4 w = *(const float4*)(posw1T + k * 64 + o0);
      const float av[4] = {a.x, a.y, a.z, a.w};
      const float wv[4] = {w.x, w.y, w.z, w.w};
#pragma unroll
      for (int i = 0; i < 4; ++i)
#pragma unroll
        for (int j = 0; j < 4; ++j) acc[i][j] = fmaf(av[i], wv[j], acc[i][j]);
    }
#pragma unroll
    for (int i = 0; i < 4; ++i)
#pragma unroll
      for (int j = 0; j < 4; ++j) {
        const float h = fmaxf(acc[i][j] + pb1s[o0 + j], 0.f);
        bufA[(o0 + j) * 64 + (m0 + i)] = h;
      }
  }
  __syncthreads();  // B2: w2T + hpT ready

  // ---- phase 3: alpha = relu(h1 @ att_w2.T + b2); ex = exp(alpha) (regs)
  float ex[4][4];
  {
    float acc[4][4] = {};
    gemm64(bufB, wbuf, m0, o0, acc);
#pragma unroll
    for (int i = 0; i < 4; ++i)
#pragma unroll
      for (int j = 0; j < 4; ++j) {
        const float al = fmaxf(acc[i][j] + b2s[o0 + j], 0.f);
        ex[i][j] = __expf(al);
      }
  }
  __syncthreads();  // B3: wbuf free

  load_wT(wbuf, pos_w2, tid);
  __syncthreads();  // B4

  // ---- phase 4: delta = relu(hp @ pos_w2.T + pb2) (regs)
  float del[4][4] = {};
  gemm64(bufA, wbuf, m0, o0, del);
#pragma unroll
  for (int i = 0; i < 4; ++i)
#pragma unroll
    for (int j = 0; j < 4; ++j)
      del[i][j] = fmaxf(del[i][j] + pb2s[o0 + j], 0.f);

  // ---- phase 5: num[dst] += ex*(v[src]+delta); den[dst] += ex
#pragma unroll
  for (int i = 0; i < 4; ++i) {
    const int el = m0 + i;
    const int e = eb + el;
    if (e < ET) {
      const int s = srcs[el];
      const int d = dsts[el];
      const float4 v4 = *(const float4*)(vv + (size_t)s * 64 + o0);
      const float vr[4] = {v4.x, v4.y, v4.z, v4.w};
#pragma unroll
      for (int j = 0; j < 4; ++j) {
        const float exv = ex[i][j];
        const float msg = exv * (vr[j] + del[i][j]);
        unsafeAtomicAdd(num + (size_t)d * 64 + o0 + j, msg);
        unsafeAtomicAdd(den + (size_t)d * 64 + o0 + j, exv);
      }
    }
  }
}

// ---------------------------------------------------------------------------
// Kernel C: out = relu((num/(den+1e-16)) @ W_out.T + b_out)
// ---------------------------------------------------------------------------
__global__ __launch_bounds__(256, 3) void out_proj(
    const float* __restrict__ num, const float* __restrict__ den,
    const float* __restrict__ W_out, const float* __restrict__ b_out,
    float* __restrict__ out) {
  __shared__ __align__(16) float bufY[64 * 64];  // yT [k][n]
  __shared__ __align__(16) float wbuf[64 * 64];
  __shared__ __align__(16) float bias[64];

  const int tid = threadIdx.x;
  const int nb = blockIdx.x * 64;
  const int m0 = (tid & 15) * 4;
  const int o0 = (tid >> 4) * 4;

  {
    const int n = tid >> 2;
    const int kc = (tid & 3) * 16;
    const int gn = nb + n;
#pragma unroll
    for (int u = 0; u < 4; ++u) {
      float4 nm = make_float4(0.f, 0.f, 0.f, 0.f);
      float4 dn = make_float4(1.f, 1.f, 1.f, 1.f);
      if (gn < NN) {
        nm = *(const float4*)(num + (size_t)gn * 64 + kc + 4 * u);
        dn = *(const float4*)(den + (size_t)gn * 64 + kc + 4 * u);
      }
      const int kb = kc + 4 * u;
      bufY[(kb + 0) * 64 + n] = nm.x / (dn.x + 1e-16f);
      bufY[(kb + 1) * 64 + n] = nm.y / (dn.y + 1e-16f);
      bufY[(kb + 2) * 64 + n] = nm.z / (dn.z + 1e-16f);
      bufY[(kb + 3) * 64 + n] = nm.w / (dn.w + 1e-16f);
    }
  }
  load_wT(wbuf, W_out, tid);
  if (tid < 64) bias[tid] = b_out[tid];
  __syncthreads();

  float acc[4][4] = {};
  gemm64(bufY, wbuf, m0, o0, acc);
#pragma unroll
  for (int i = 0; i < 4; ++i) {
    const int gn = nb + m0 + i;
    if (gn < NN) {
      float4 r;
      r.x = fmaxf(acc[i][0] + bias[o0 + 0], 0.f);
      r.y = fmaxf(acc[i][1] + bias[o0 + 1], 0.f);
      r.z = fmaxf(acc[i][2] + bias[o0 + 2], 0.f);
      r.w = fmaxf(acc[i][3] + bias[o0 + 3], 0.f);
      *(float4*)(out + (size_t)gn * 64 + o0) = r;
    }
  }
}

extern "C" void kernel_launch(void* const* d_in, const int* in_sizes, int n_in,
                              void* d_out, int out_size, void* d_ws,
                              size_t ws_size, hipStream_t stream) {
  const float* x      = (const float*)d_in[0];
  const float* pos    = (const float*)d_in[1];
  const int*   ei     = (const int*)d_in[2];
  const float* W_in   = (const float*)d_in[3];
  const float* b_in   = (const float*)d_in[4];
  const float* W_out  = (const float*)d_in[5];
  const float* b_out  = (const float*)d_in[6];
  const float* W_lin  = (const float*)d_in[7];
  const float* W_src  = (const float*)d_in[8];
  const float* W_dst  = (const float*)d_in[9];
  const float* pos_w1 = (const float*)d_in[10];
  const float* pos_b1 = (const float*)d_in[11];
  const float* pos_w2 = (const float*)d_in[12];
  const float* pos_b2 = (const float*)d_in[13];
  const float* att_w1 = (const float*)d_in[14];
  const float* att_b1 = (const float*)d_in[15];
  const float* att_w2 = (const float*)d_in[16];
  const float* att_b2 = (const float*)d_in[17];

  float* ws = (float*)d_ws;
  const size_t NC = (size_t)NN * C;
  float* v   = ws;
  float* kk  = ws + NC;
  float* q   = ws + 2 * NC;
  float* num = ws + 3 * NC;
  float* den = ws + 4 * NC;

  // zero the atomic accumulators (ws is poisoned 0xAA before every call)
  hipMemsetAsync(num, 0, 2 * NC * sizeof(float), stream);

  const dim3 blk(256);
  node_proj<<<dim3((NN + 63) / 64), blk, 0, stream>>>(x, W_in, b_in, W_lin,
                                                      W_src, W_dst, v, kk, q);
  edge_pass<<<dim3((ET + 63) / 64), blk, 0, stream>>>(
      ei, pos, v, kk, q, att_w1, att_b1, att_w2, att_b2, pos_w1, pos_b1,
      pos_w2, pos_b2, num, den);
  out_proj<<<dim3((NN + 63) / 64), blk, 0, stream>>>(num, den, W_out, b_out,
                                                     (float*)d_out);
}

// Round 2
// 684.855 us; speedup vs baseline: 2.3160x; 2.3160x over previous
//
#include <hip/hip_runtime.h>
#include <math.h>

#define NN 50000
#define EE 800000
#define ET (EE + NN)   // 850000 edges incl. self-loops
#define C  64

// ---------------------------------------------------------------------------
// GEMM microkernel: out[m][o] = sum_k AT[k*64+m] * WT[k*64+o]  (stride 64)
// ---------------------------------------------------------------------------
__device__ __forceinline__ void gemm64(const float* __restrict__ AT,
                                       const float* __restrict__ WT,
                                       int m0, int o0, float acc[4][4]) {
#pragma unroll 8
  for (int k = 0; k < 64; ++k) {
    const float4 a = *(const float4*)(AT + k * 64 + m0);
    const float4 w = *(const float4*)(WT + k * 64 + o0);
    const float av[4] = {a.x, a.y, a.z, a.w};
    const float wv[4] = {w.x, w.y, w.z, w.w};
#pragma unroll
    for (int i = 0; i < 4; ++i)
#pragma unroll
      for (int j = 0; j < 4; ++j) acc[i][j] = fmaf(av[i], wv[j], acc[i][j]);
  }
}

// Load 64x64 row-major weight W[o][k], store transposed WT[k][o] (stride 64).
__device__ __forceinline__ void load_wT(float* __restrict__ dst,
                                        const float* __restrict__ W, int tid) {
  const int o = tid >> 2;
  const int kc = (tid & 3) * 16;
  const float4* src = (const float4*)(W + o * 64 + kc);
#pragma unroll
  for (int u = 0; u < 4; ++u) {
    const float4 wv = src[u];
    const int kb = kc + 4 * u;
    dst[(kb + 0) * 64 + o] = wv.x;
    dst[(kb + 1) * 64 + o] = wv.y;
    dst[(kb + 2) * 64 + o] = wv.z;
    dst[(kb + 3) * 64 + o] = wv.w;
  }
}

// ---------------------------------------------------------------------------
// Sort-by-dst machinery: histogram -> exclusive scan -> scatter (counting sort)
// ---------------------------------------------------------------------------
__global__ void hist_kernel(const int* __restrict__ ei, int* __restrict__ cnt) {
  const int e = blockIdx.x * 256 + threadIdx.x;
  if (e >= ET) return;
  const int d = (e < EE) ? ei[EE + e] : (e - EE);
  atomicAdd(&cnt[d], 1);
}

__global__ __launch_bounds__(1024) void scan_kernel(const int* __restrict__ cnt,
                                                    int* __restrict__ curs) {
  __shared__ int sums[1024];
  const int t = threadIdx.x;
  const int CH = (NN + 1023) / 1024;  // 49
  const int base = t * CH;
  int s = 0;
  for (int i = 0; i < CH; ++i) {
    const int idx = base + i;
    if (idx < NN) s += cnt[idx];
  }
  sums[t] = s;
  __syncthreads();
  for (int off = 1; off < 1024; off <<= 1) {
    const int v = (t >= off) ? sums[t - off] : 0;
    __syncthreads();
    sums[t] += v;
    __syncthreads();
  }
  int run = (t > 0) ? sums[t - 1] : 0;
  for (int i = 0; i < CH; ++i) {
    const int idx = base + i;
    if (idx < NN) {
      curs[idx] = run;
      run += cnt[idx];
    }
  }
}

__global__ void scatter_kernel(const int* __restrict__ ei,
                               int* __restrict__ curs, int2* __restrict__ srt) {
  const int e = blockIdx.x * 256 + threadIdx.x;
  if (e >= ET) return;
  int s, d;
  if (e < EE) {
    s = ei[e];
    d = ei[EE + e];
  } else {
    s = e - EE;
    d = s;
  }
  const int p = atomicAdd(&curs[d], 1);
  srt[p] = make_int2(s, d);
}

// ---------------------------------------------------------------------------
// Kernel A: h = relu(x@W_in.T + b_in); v = h@W_lin.T; k = h@W_src.T; q = h@W_dst.T
// ---------------------------------------------------------------------------
__global__ __launch_bounds__(256, 3) void node_proj(
    const float* __restrict__ x, const float* __restrict__ W_in,
    const float* __restrict__ b_in, const float* __restrict__ W_lin,
    const float* __restrict__ W_src, const float* __restrict__ W_dst,
    float* __restrict__ v, float* __restrict__ kk, float* __restrict__ q) {
  __shared__ __align__(16) float bufX[64 * 64];
  __shared__ __align__(16) float bufH[64 * 64];
  __shared__ __align__(16) float wbuf[64 * 64];
  __shared__ __align__(16) float bias[64];

  const int tid = threadIdx.x;
  const int nb = blockIdx.x * 64;
  const int m0 = (tid & 15) * 4;
  const int o0 = (tid >> 4) * 4;

  {
    const int n = tid >> 2;
    const int kc = (tid & 3) * 16;
    const int gn = nb + n;
#pragma unroll
    for (int u = 0; u < 4; ++u) {
      float4 xv = make_float4(0.f, 0.f, 0.f, 0.f);
      if (gn < NN) xv = *(const float4*)(x + (size_t)gn * 64 + kc + 4 * u);
      const int kb = kc + 4 * u;
      bufX[(kb + 0) * 64 + n] = xv.x;
      bufX[(kb + 1) * 64 + n] = xv.y;
      bufX[(kb + 2) * 64 + n] = xv.z;
      bufX[(kb + 3) * 64 + n] = xv.w;
    }
  }
  load_wT(wbuf, W_in, tid);
  if (tid < 64) bias[tid] = b_in[tid];
  __syncthreads();

  float acc[4][4] = {};
  gemm64(bufX, wbuf, m0, o0, acc);
#pragma unroll
  for (int i = 0; i < 4; ++i)
#pragma unroll
    for (int j = 0; j < 4; ++j) {
      const float h = fmaxf(acc[i][j] + bias[o0 + j], 0.f);
      bufH[(o0 + j) * 64 + (m0 + i)] = h;
    }
  __syncthreads();

  const float* Ws[3] = {W_lin, W_src, W_dst};
  float* outs[3] = {v, kk, q};
#pragma unroll 1
  for (int p = 0; p < 3; ++p) {
    load_wT(wbuf, Ws[p], tid);
    __syncthreads();
    float a2[4][4] = {};
    gemm64(bufH, wbuf, m0, o0, a2);
#pragma unroll
    for (int i = 0; i < 4; ++i) {
      const int gn = nb + m0 + i;
      if (gn < NN) {
        const float4 r = make_float4(a2[i][0], a2[i][1], a2[i][2], a2[i][3]);
        *(float4*)(outs[p] + (size_t)gn * 64 + o0) = r;
      }
    }
    __syncthreads();
  }
}

// ---------------------------------------------------------------------------
// Kernel B: fused per-edge MLPs + exp + LDS segmented reduction + atomics.
// Edges are SORTED by dst -> a block's 64 edges span only ~4-7 dst segments.
// ---------------------------------------------------------------------------
__global__ __launch_bounds__(256, 3) void edge_pass(
    const int2* __restrict__ srt, const float* __restrict__ pos,
    const float* __restrict__ vv, const float* __restrict__ kk,
    const float* __restrict__ qq, const float* __restrict__ att_w1,
    const float* __restrict__ att_b1, const float* __restrict__ att_w2,
    const float* __restrict__ att_b2, const float* __restrict__ pos_w1,
    const float* __restrict__ pos_b1, const float* __restrict__ pos_w2,
    const float* __restrict__ pos_b2, float* __restrict__ num,
    float* __restrict__ den) {
  __shared__ __align__(16) float bufA[64 * 65];  // gemm scratch (stride 64) / msg (stride 65)
  __shared__ __align__(16) float bufB[64 * 65];  // gemm scratch (stride 64) / ex  (stride 65)
  __shared__ __align__(16) float wbuf[64 * 64];
  __shared__ __align__(16) float posw1T[3 * 64];
  __shared__ __align__(16) float dpT[3 * 64];
  __shared__ __align__(16) float b1s[64], b2s[64], pb1s[64], pb2s[64];
  __shared__ int srcs[64], dstsR[64];

  const int tid = threadIdx.x;
  const int eb = blockIdx.x * 64;
  const int m0 = (tid & 15) * 4;
  const int o0 = (tid >> 4) * 4;

  // ---- phase 0: gather ad = q[dst]-k[src], dp = pos[dst]-pos[src], weights
  {
    const int el = tid >> 2;
    const int e = eb + el;
    const int kc = (tid & 3) * 16;
    int s = 0, d = -1;
    if (e < ET) {
      const int2 sd = srt[e];
      s = sd.x;
      d = sd.y;
    }
    const int d0 = (d < 0) ? 0 : d;
    if ((tid & 3) == 0) {
      srcs[el] = s;
      dstsR[el] = d;
      dpT[0 * 64 + el] = pos[(size_t)d0 * 3 + 0] - pos[(size_t)s * 3 + 0];
      dpT[1 * 64 + el] = pos[(size_t)d0 * 3 + 1] - pos[(size_t)s * 3 + 1];
      dpT[2 * 64 + el] = pos[(size_t)d0 * 3 + 2] - pos[(size_t)s * 3 + 2];
    }
    const float4* qp = (const float4*)(qq + (size_t)d0 * 64 + kc);
    const float4* kp = (const float4*)(kk + (size_t)s * 64 + kc);
#pragma unroll
    for (int u = 0; u < 4; ++u) {
      const float4 a = qp[u];
      const float4 b = kp[u];
      const int kb = kc + 4 * u;
      bufA[(kb + 0) * 64 + el] = a.x - b.x;
      bufA[(kb + 1) * 64 + el] = a.y - b.y;
      bufA[(kb + 2) * 64 + el] = a.z - b.z;
      bufA[(kb + 3) * 64 + el] = a.w - b.w;
    }
  }
  if (tid < 64) {
    b1s[tid] = att_b1[tid];
    b2s[tid] = att_b2[tid];
    pb1s[tid] = pos_b1[tid];
    pb2s[tid] = pos_b2[tid];
    posw1T[0 * 64 + tid] = pos_w1[tid * 3 + 0];
    posw1T[1 * 64 + tid] = pos_w1[tid * 3 + 1];
    posw1T[2 * 64 + tid] = pos_w1[tid * 3 + 2];
  }
  load_wT(wbuf, att_w1, tid);
  __syncthreads();  // B0

  // ---- phase 1: h1 = relu(ad @ att_w1.T + b1) -> bufB
  {
    float acc[4][4] = {};
    gemm64(bufA, wbuf, m0, o0, acc);
#pragma unroll
    for (int i = 0; i < 4; ++i)
#pragma unroll
      for (int j = 0; j < 4; ++j) {
        const float h = fmaxf(acc[i][j] + b1s[o0 + j], 0.f);
        bufB[(o0 + j) * 64 + (m0 + i)] = h;
      }
  }
  __syncthreads();  // B1: bufA & wbuf free

  load_wT(wbuf, att_w2, tid);
  // ---- phase 2: hp = relu(dp @ pos_w1.T + pb1) (k=3) -> bufA
  {
    float acc[4][4] = {};
#pragma unroll
    for (int k = 0; k < 3; ++k) {
      const float4 a = *(const float4*)(dpT + k * 64 + m0);
      const float4 w = *(const float4*)(posw1T + k * 64 + o0);
      const float av[4] = {a.x, a.y, a.z, a.w};
      const float wv[4] = {w.x, w.y, w.z, w.w};
#pragma unroll
      for (int i = 0; i < 4; ++i)
#pragma unroll
        for (int j = 0; j < 4; ++j) acc[i][j] = fmaf(av[i], wv[j], acc[i][j]);
    }
#pragma unroll
    for (int i = 0; i < 4; ++i)
#pragma unroll
      for (int j = 0; j < 4; ++j) {
        const float h = fmaxf(acc[i][j] + pb1s[o0 + j], 0.f);
        bufA[(o0 + j) * 64 + (m0 + i)] = h;
      }
  }
  __syncthreads();  // B2

  // ---- phase 3: alpha = relu(h1 @ att_w2.T + b2); ex = exp(alpha)
  float ex[4][4];
  {
    float acc[4][4] = {};
    gemm64(bufB, wbuf, m0, o0, acc);
#pragma unroll
    for (int i = 0; i < 4; ++i)
#pragma unroll
      for (int j = 0; j < 4; ++j) {
        const float al = fmaxf(acc[i][j] + b2s[o0 + j], 0.f);
        ex[i][j] = __expf(al);
      }
  }
  __syncthreads();  // B3

  load_wT(wbuf, pos_w2, tid);
  __syncthreads();  // B4

  // ---- phase 4: delta = relu(hp @ pos_w2.T + pb2)
  float del[4][4] = {};
  gemm64(bufA, wbuf, m0, o0, del);
#pragma unroll
  for (int i = 0; i < 4; ++i)
#pragma unroll
    for (int j = 0; j < 4; ++j)
      del[i][j] = fmaxf(del[i][j] + pb2s[o0 + j], 0.f);

  __syncthreads();  // B5: bufA/bufB gemm reads done, reuse as stride-65 scratch

  // ---- phase 5: msg/ex -> LDS (stride 65; j-rotated to stagger banks)
#pragma unroll
  for (int i = 0; i < 4; ++i) {
    const int el = m0 + i;
    const int s = srcs[el];
    const float4 v4 = *(const float4*)(vv + (size_t)s * 64 + o0);
    const float vr[4] = {v4.x, v4.y, v4.z, v4.w};
#pragma unroll
    for (int jj = 0; jj < 4; ++jj) {
      const int j = (jj + (tid & 15)) & 3;
      bufB[(o0 + j) * 65 + el] = ex[i][j];
      bufA[(o0 + j) * 65 + el] = ex[i][j] * (vr[j] + del[i][j]);
    }
  }
  __syncthreads();  // B6

  // ---- phase 6: segmented reduce over sorted-dst runs, then atomics.
  // lane c = channel, r = 16-edge run; lanes of a wave share the dst sequence
  // -> flushes are wave-coalesced across 64 consecutive channels.
  {
    const int c = tid & 63;
    const int r = tid >> 6;
    float am = 0.f, ae = 0.f;
    int cur = -1;
    for (int t2 = 0; t2 < 16; ++t2) {
      const int el = r * 16 + t2;
      const int d = dstsR[el];
      if (d != cur) {
        if (cur >= 0) {
          unsafeAtomicAdd(num + (size_t)cur * 64 + c, am);
          unsafeAtomicAdd(den + (size_t)cur * 64 + c, ae);
        }
        cur = d;
        am = 0.f;
        ae = 0.f;
      }
      if (d >= 0) {
        am += bufA[c * 65 + el];
        ae += bufB[c * 65 + el];
      }
    }
    if (cur >= 0) {
      unsafeAtomicAdd(num + (size_t)cur * 64 + c, am);
      unsafeAtomicAdd(den + (size_t)cur * 64 + c, ae);
    }
  }
}

// ---------------------------------------------------------------------------
// Kernel C: out = relu((num/(den+1e-16)) @ W_out.T + b_out)
// ---------------------------------------------------------------------------
__global__ __launch_bounds__(256, 3) void out_proj(
    const float* __restrict__ num, const float* __restrict__ den,
    const float* __restrict__ W_out, const float* __restrict__ b_out,
    float* __restrict__ out) {
  __shared__ __align__(16) float bufY[64 * 64];
  __shared__ __align__(16) float wbuf[64 * 64];
  __shared__ __align__(16) float bias[64];

  const int tid = threadIdx.x;
  const int nb = blockIdx.x * 64;
  const int m0 = (tid & 15) * 4;
  const int o0 = (tid >> 4) * 4;

  {
    const int n = tid >> 2;
    const int kc = (tid & 3) * 16;
    const int gn = nb + n;
#pragma unroll
    for (int u = 0; u < 4; ++u) {
      float4 nm = make_float4(0.f, 0.f, 0.f, 0.f);
      float4 dn = make_float4(1.f, 1.f, 1.f, 1.f);
      if (gn < NN) {
        nm = *(const float4*)(num + (size_t)gn * 64 + kc + 4 * u);
        dn = *(const float4*)(den + (size_t)gn * 64 + kc + 4 * u);
      }
      const int kb = kc + 4 * u;
      bufY[(kb + 0) * 64 + n] = nm.x / (dn.x + 1e-16f);
      bufY[(kb + 1) * 64 + n] = nm.y / (dn.y + 1e-16f);
      bufY[(kb + 2) * 64 + n] = nm.z / (dn.z + 1e-16f);
      bufY[(kb + 3) * 64 + n] = nm.w / (dn.w + 1e-16f);
    }
  }
  load_wT(wbuf, W_out, tid);
  if (tid < 64) bias[tid] = b_out[tid];
  __syncthreads();

  float acc[4][4] = {};
  gemm64(bufY, wbuf, m0, o0, acc);
#pragma unroll
  for (int i = 0; i < 4; ++i) {
    const int gn = nb + m0 + i;
    if (gn < NN) {
      float4 r;
      r.x = fmaxf(acc[i][0] + bias[o0 + 0], 0.f);
      r.y = fmaxf(acc[i][1] + bias[o0 + 1], 0.f);
      r.z = fmaxf(acc[i][2] + bias[o0 + 2], 0.f);
      r.w = fmaxf(acc[i][3] + bias[o0 + 3], 0.f);
      *(float4*)(out + (size_t)gn * 64 + o0) = r;
    }
  }
}

extern "C" void kernel_launch(void* const* d_in, const int* in_sizes, int n_in,
                              void* d_out, int out_size, void* d_ws,
                              size_t ws_size, hipStream_t stream) {
  const float* x      = (const float*)d_in[0];
  const float* pos    = (const float*)d_in[1];
  const int*   ei     = (const int*)d_in[2];
  const float* W_in   = (const float*)d_in[3];
  const float* b_in   = (const float*)d_in[4];
  const float* W_out  = (const float*)d_in[5];
  const float* b_out  = (const float*)d_in[6];
  const float* W_lin  = (const float*)d_in[7];
  const float* W_src  = (const float*)d_in[8];
  const float* W_dst  = (const float*)d_in[9];
  const float* pos_w1 = (const float*)d_in[10];
  const float* pos_b1 = (const float*)d_in[11];
  const float* pos_w2 = (const float*)d_in[12];
  const float* pos_b2 = (const float*)d_in[13];
  const float* att_w1 = (const float*)d_in[14];
  const float* att_b1 = (const float*)d_in[15];
  const float* att_w2 = (const float*)d_in[16];
  const float* att_b2 = (const float*)d_in[17];

  float* ws = (float*)d_ws;
  const size_t NC = (size_t)NN * C;
  float* v   = ws;
  float* kk  = ws + NC;
  float* q   = ws + 2 * NC;
  float* num = ws + 3 * NC;
  float* den = ws + 4 * NC;
  int* ib    = (int*)(ws + 5 * NC);
  int* cnt   = ib;            // NN
  int* curs  = ib + NN;       // NN
  int2* srt  = (int2*)(ib + 2 * NN);  // ET int2

  hipMemsetAsync(num, 0, 2 * NC * sizeof(float), stream);
  hipMemsetAsync(cnt, 0, NN * sizeof(int), stream);

  const dim3 blk(256);
  node_proj<<<dim3((NN + 63) / 64), blk, 0, stream>>>(x, W_in, b_in, W_lin,
                                                      W_src, W_dst, v, kk, q);
  hist_kernel<<<dim3((ET + 255) / 256), blk, 0, stream>>>(ei, cnt);
  scan_kernel<<<dim3(1), dim3(1024), 0, stream>>>(cnt, curs);
  scatter_kernel<<<dim3((ET + 255) / 256), blk, 0, stream>>>(ei, curs, srt);
  edge_pass<<<dim3((ET + 63) / 64), blk, 0, stream>>>(
      srt, pos, v, kk, q, att_w1, att_b1, att_w2, att_b2, pos_w1, pos_b1,
      pos_w2, pos_b2, num, den);
  out_proj<<<dim3((NN + 63) / 64), blk, 0, stream>>>(num, den, W_out, b_out,
                                                     (float*)d_out);
}

// Round 3
// 460.213 us; speedup vs baseline: 3.4465x; 1.4881x over previous
//
#include <hip/hip_runtime.h>
#include <math.h>

#define NN 50000
#define EE 800000
#define ET (EE + NN)   // 850000 edges incl. self-loops
#define C  64

typedef __attribute__((ext_vector_type(8))) short bf16x8;
typedef __attribute__((ext_vector_type(4))) float f32x4;

__device__ __forceinline__ unsigned short f2bf(float f) {
  union { float f; unsigned u; } c; c.f = f;
  unsigned u = c.u;
  u += 0x7FFF + ((u >> 16) & 1);  // RNE
  return (unsigned short)(u >> 16);
}
__device__ __forceinline__ float bf2f(unsigned u16) {
  union { unsigned u; float f; } c; c.u = u16 << 16;
  return c.f;
}

// a,b are 8 packed bf16 (uint4); return bf16x8 of (a-b) rounded to bf16
__device__ __forceinline__ bf16x8 sub_bf8(uint4 a, uint4 b) {
  bf16x8 r;
  const unsigned* pa = (const unsigned*)&a;
  const unsigned* pb = (const unsigned*)&b;
#pragma unroll
  for (int i = 0; i < 4; ++i) {
    const float alo = bf2f(pa[i] & 0xFFFFu), ahi = bf2f(pa[i] >> 16);
    const float blo = bf2f(pb[i] & 0xFFFFu), bhi = bf2f(pb[i] >> 16);
    r[2 * i]     = (short)f2bf(alo - blo);
    r[2 * i + 1] = (short)f2bf(ahi - bhi);
  }
  return r;
}

// stride-72 bf16 LDS row read: 8 consecutive k at 16B alignment
__device__ __forceinline__ bf16x8 frag_ld(const unsigned short* base, int row,
                                          int kofs) {
  return *(const bf16x8*)(base + row * 72 + kofs);
}

// fp32 64x64 row-major weight -> bf16 LDS, stride 72 (144B rows: 2-way banks)
__device__ __forceinline__ void load_wbf(unsigned short* __restrict__ dst,
                                         const float* __restrict__ W, int tid) {
  const int o = tid >> 2;
  const int kc = (tid & 3) * 16;
  const float4* src = (const float4*)(W + o * 64 + kc);
  ushort4* d = (ushort4*)(dst + o * 72 + kc);
#pragma unroll
  for (int u = 0; u < 4; ++u) {
    const float4 w = src[u];
    ushort4 pk;
    pk.x = f2bf(w.x); pk.y = f2bf(w.y); pk.z = f2bf(w.z); pk.w = f2bf(w.w);
    d[u] = pk;
  }
}

// ---------------------------------------------------------------------------
// fp32 GEMM microkernel (node/out projections only)
// ---------------------------------------------------------------------------
__device__ __forceinline__ void gemm64(const float* __restrict__ AT,
                                       const float* __restrict__ WT,
                                       int m0, int o0, float acc[4][4]) {
#pragma unroll 8
  for (int k = 0; k < 64; ++k) {
    const float4 a = *(const float4*)(AT + k * 64 + m0);
    const float4 w = *(const float4*)(WT + k * 64 + o0);
    const float av[4] = {a.x, a.y, a.z, a.w};
    const float wv[4] = {w.x, w.y, w.z, w.w};
#pragma unroll
    for (int i = 0; i < 4; ++i)
#pragma unroll
      for (int j = 0; j < 4; ++j) acc[i][j] = fmaf(av[i], wv[j], acc[i][j]);
  }
}

__device__ __forceinline__ void load_wT(float* __restrict__ dst,
                                        const float* __restrict__ W, int tid) {
  const int o = tid >> 2;
  const int kc = (tid & 3) * 16;
  const float4* src = (const float4*)(W + o * 64 + kc);
#pragma unroll
  for (int u = 0; u < 4; ++u) {
    const float4 wv = src[u];
    const int kb = kc + 4 * u;
    dst[(kb + 0) * 64 + o] = wv.x;
    dst[(kb + 1) * 64 + o] = wv.y;
    dst[(kb + 2) * 64 + o] = wv.z;
    dst[(kb + 3) * 64 + o] = wv.w;
  }
}

// ---------------------------------------------------------------------------
// Counting sort by dst: histogram -> scan -> scatter
// ---------------------------------------------------------------------------
__global__ void hist_kernel(const int* __restrict__ ei, int* __restrict__ cnt) {
  const int e = blockIdx.x * 256 + threadIdx.x;
  if (e >= ET) return;
  const int d = (e < EE) ? ei[EE + e] : (e - EE);
  atomicAdd(&cnt[d], 1);
}

__global__ __launch_bounds__(1024) void scan_kernel(const int* __restrict__ cnt,
                                                    int* __restrict__ curs) {
  __shared__ int sums[1024];
  const int t = threadIdx.x;
  const int CH = (NN + 1023) / 1024;
  const int base = t * CH;
  int s = 0;
  for (int i = 0; i < CH; ++i) {
    const int idx = base + i;
    if (idx < NN) s += cnt[idx];
  }
  sums[t] = s;
  __syncthreads();
  for (int off = 1; off < 1024; off <<= 1) {
    const int v = (t >= off) ? sums[t - off] : 0;
    __syncthreads();
    sums[t] += v;
    __syncthreads();
  }
  int run = (t > 0) ? sums[t - 1] : 0;
  for (int i = 0; i < CH; ++i) {
    const int idx = base + i;
    if (idx < NN) {
      curs[idx] = run;
      run += cnt[idx];
    }
  }
}

__global__ void scatter_kernel(const int* __restrict__ ei,
                               int* __restrict__ curs, int2* __restrict__ srt) {
  const int e = blockIdx.x * 256 + threadIdx.x;
  if (e >= ET) return;
  int s, d;
  if (e < EE) {
    s = ei[e];
    d = ei[EE + e];
  } else {
    s = e - EE;
    d = s;
  }
  const int p = atomicAdd(&curs[d], 1);
  srt[p] = make_int2(s, d);
}

// ---------------------------------------------------------------------------
// Kernel A: h = relu(x@W_in.T+b); v = h@W_lin.T (f32); k/q = h@W_{src,dst}.T (bf16)
// ---------------------------------------------------------------------------
__global__ __launch_bounds__(256, 3) void node_proj(
    const float* __restrict__ x, const float* __restrict__ W_in,
    const float* __restrict__ b_in, const float* __restrict__ W_lin,
    const float* __restrict__ W_src, const float* __restrict__ W_dst,
    float* __restrict__ v, unsigned short* __restrict__ kb,
    unsigned short* __restrict__ qb) {
  __shared__ __align__(16) float bufX[64 * 64];
  __shared__ __align__(16) float bufH[64 * 64];
  __shared__ __align__(16) float wbuf[64 * 64];
  __shared__ __align__(16) float bias[64];

  const int tid = threadIdx.x;
  const int nb = blockIdx.x * 64;
  const int m0 = (tid & 15) * 4;
  const int o0 = (tid >> 4) * 4;

  {
    const int n = tid >> 2;
    const int kc = (tid & 3) * 16;
    const int gn = nb + n;
#pragma unroll
    for (int u = 0; u < 4; ++u) {
      float4 xv = make_float4(0.f, 0.f, 0.f, 0.f);
      if (gn < NN) xv = *(const float4*)(x + (size_t)gn * 64 + kc + 4 * u);
      const int kbi = kc + 4 * u;
      bufX[(kbi + 0) * 64 + n] = xv.x;
      bufX[(kbi + 1) * 64 + n] = xv.y;
      bufX[(kbi + 2) * 64 + n] = xv.z;
      bufX[(kbi + 3) * 64 + n] = xv.w;
    }
  }
  load_wT(wbuf, W_in, tid);
  if (tid < 64) bias[tid] = b_in[tid];
  __syncthreads();

  float acc[4][4] = {};
  gemm64(bufX, wbuf, m0, o0, acc);
#pragma unroll
  for (int i = 0; i < 4; ++i)
#pragma unroll
    for (int j = 0; j < 4; ++j) {
      const float h = fmaxf(acc[i][j] + bias[o0 + j], 0.f);
      bufH[(o0 + j) * 64 + (m0 + i)] = h;
    }
  __syncthreads();

  const float* Ws[3] = {W_lin, W_src, W_dst};
#pragma unroll 1
  for (int p = 0; p < 3; ++p) {
    load_wT(wbuf, Ws[p], tid);
    __syncthreads();
    float a2[4][4] = {};
    gemm64(bufH, wbuf, m0, o0, a2);
#pragma unroll
    for (int i = 0; i < 4; ++i) {
      const int gn = nb + m0 + i;
      if (gn < NN) {
        if (p == 0) {
          const float4 r = make_float4(a2[i][0], a2[i][1], a2[i][2], a2[i][3]);
          *(float4*)(v + (size_t)gn * 64 + o0) = r;
        } else {
          ushort4 pk;
          pk.x = f2bf(a2[i][0]); pk.y = f2bf(a2[i][1]);
          pk.z = f2bf(a2[i][2]); pk.w = f2bf(a2[i][3]);
          unsigned short* dst = (p == 1) ? kb : qb;
          *(ushort4*)(dst + (size_t)gn * 64 + o0) = pk;
        }
      }
    }
    __syncthreads();
  }
}

// ---------------------------------------------------------------------------
// Kernel B: MFMA edge pass. Wave w owns edges [w*16, w*16+16) of the block's
// 64; computes D[out][edge] tiles (16x16x32 bf16 MFMA, m89 C/D layout).
// ---------------------------------------------------------------------------
__global__ __launch_bounds__(256, 4) void edge_pass(
    const int2* __restrict__ srt, const float* __restrict__ pos,
    const float* __restrict__ vv, const unsigned short* __restrict__ kb,
    const unsigned short* __restrict__ qb, const float* __restrict__ att_w1,
    const float* __restrict__ att_b1, const float* __restrict__ att_w2,
    const float* __restrict__ att_b2, const float* __restrict__ pos_w1,
    const float* __restrict__ pos_b1, const float* __restrict__ pos_w2,
    const float* __restrict__ pos_b2, float* __restrict__ num,
    float* __restrict__ den) {
  // 36864B region: W1(->hp) | W2 | PW2 | h1, each 64 rows x stride 72 bf16.
  // After B1 it is reused as msgb/exb (2 x 64x65 f32 = 33280B).
  __shared__ __align__(16) unsigned short smem[18432];
  __shared__ __align__(16) float dpT[3 * 64];
  __shared__ __align__(16) float posw1T[3 * 64];
  __shared__ float b1s[64], b2s[64], pb1s[64], pb2s[64];
  __shared__ int srcs[64], dsts[64];

  unsigned short* W1  = smem;          // later: hp
  unsigned short* W2  = smem + 4608;
  unsigned short* PW2 = smem + 9216;
  unsigned short* h1  = smem + 13824;
  float* msgb = (float*)smem;          // 64*65 f32
  float* exb  = ((float*)smem) + 64 * 65;

  const int tid = threadIdx.x;
  const int eb = blockIdx.x * 64;
  const int l15 = tid & 15;
  const int quad = (tid >> 4) & 3;
  const int wband = tid >> 6;
  const int eloc = wband * 16 + l15;  // this lane's edge (block-local)

  // ---- phase 0a: per-lane B-frag gather: ad = q[dst]-k[src] (bf16 global)
  int s_mine, d_mine;
  bf16x8 bfrag[2];
  {
    const int e = eb + eloc;
    int2 sd = make_int2(0, 0);
    if (e < ET) sd = srt[e];
    s_mine = sd.x;
    d_mine = sd.y;
#pragma unroll
    for (int ks = 0; ks < 2; ++ks) {
      const uint4 qv =
          *(const uint4*)(qb + (size_t)d_mine * 64 + ks * 32 + quad * 8);
      const uint4 kv =
          *(const uint4*)(kb + (size_t)s_mine * 64 + ks * 32 + quad * 8);
      bfrag[ks] = sub_bf8(qv, kv);
    }
  }

  // ---- phase 0b: stage weights (bf16), biases, per-edge indices, dp
  load_wbf(W1, att_w1, tid);
  load_wbf(W2, att_w2, tid);
  load_wbf(PW2, pos_w2, tid);
  if (tid < 64) {
    b1s[tid] = att_b1[tid];
    b2s[tid] = att_b2[tid];
    pb1s[tid] = pos_b1[tid];
    pb2s[tid] = pos_b2[tid];
    posw1T[0 * 64 + tid] = pos_w1[tid * 3 + 0];
    posw1T[1 * 64 + tid] = pos_w1[tid * 3 + 1];
    posw1T[2 * 64 + tid] = pos_w1[tid * 3 + 2];
  }
  if ((tid & 3) == 0) {
    const int el = tid >> 2;
    const int e = eb + el;
    int s = 0, d = -1;
    if (e < ET) {
      const int2 sd = srt[e];
      s = sd.x;
      d = sd.y;
    }
    srcs[el] = s;
    dsts[el] = d;
    const int d0 = (d < 0) ? 0 : d;
    dpT[0 * 64 + el] = pos[(size_t)d0 * 3 + 0] - pos[(size_t)s * 3 + 0];
    dpT[1 * 64 + el] = pos[(size_t)d0 * 3 + 1] - pos[(size_t)s * 3 + 1];
    dpT[2 * 64 + el] = pos[(size_t)d0 * 3 + 2] - pos[(size_t)s * 3 + 2];
  }
  __syncthreads();  // B0

  // ---- GEMM1: h1[h][e] = relu(W1 . ad^T + b1) -> h1 LDS rows [e][h] bf16
#pragma unroll
  for (int t = 0; t < 4; ++t) {
    f32x4 acc = {0.f, 0.f, 0.f, 0.f};
#pragma unroll
    for (int ks = 0; ks < 2; ++ks) {
      const bf16x8 af = frag_ld(W1, t * 16 + l15, ks * 32 + quad * 8);
      acc = __builtin_amdgcn_mfma_f32_16x16x32_bf16(af, bfrag[ks], acc, 0, 0, 0);
    }
    const int hb = t * 16 + quad * 4;
    ushort4 pk;
    pk.x = f2bf(fmaxf(acc[0] + b1s[hb + 0], 0.f));
    pk.y = f2bf(fmaxf(acc[1] + b1s[hb + 1], 0.f));
    pk.z = f2bf(fmaxf(acc[2] + b1s[hb + 2], 0.f));
    pk.w = f2bf(fmaxf(acc[3] + b1s[hb + 3], 0.f));
    *(ushort4*)(h1 + eloc * 72 + hb) = pk;
  }
  __syncthreads();  // B0.5: W1 reads complete -> region becomes hp

  // ---- phase 2: hp = relu(dp @ pos_w1.T + pb1) (k=3, VALU) -> hp rows bf16
  {
    const int m0 = (tid & 15) * 4;  // edge
    const int o0 = (tid >> 4) * 4;  // hidden
    float acc[4][4] = {};
#pragma unroll
    for (int k = 0; k < 3; ++k) {
      const float4 a = *(const float4*)(dpT + k * 64 + m0);
      const float4 w = *(const float4*)(posw1T + k * 64 + o0);
      const float av[4] = {a.x, a.y, a.z, a.w};
      const float wv[4] = {w.x, w.y, w.z, w.w};
#pragma unroll
      for (int i = 0; i < 4; ++i)
#pragma unroll
        for (int j = 0; j < 4; ++j) acc[i][j] = fmaf(av[i], wv[j], acc[i][j]);
    }
    unsigned short* hp = W1;
#pragma unroll
    for (int i = 0; i < 4; ++i) {
      ushort4 pk;
      pk.x = f2bf(fmaxf(acc[i][0] + pb1s[o0 + 0], 0.f));
      pk.y = f2bf(fmaxf(acc[i][1] + pb1s[o0 + 1], 0.f));
      pk.z = f2bf(fmaxf(acc[i][2] + pb1s[o0 + 2], 0.f));
      pk.w = f2bf(fmaxf(acc[i][3] + pb1s[o0 + 3], 0.f));
      *(ushort4*)(hp + (m0 + i) * 72 + o0) = pk;
    }
  }
  __syncthreads();  // B0.75: hp visible

  // ---- GEMM2: alpha = relu(W2 . h1^T + b2); ex = exp(alpha)  (regs)
  float ex[16], del[16];
  {
    bf16x8 hfrag[2];
#pragma unroll
    for (int ks = 0; ks < 2; ++ks)
      hfrag[ks] = frag_ld(h1, eloc, ks * 32 + quad * 8);
#pragma unroll
    for (int t = 0; t < 4; ++t) {
      f32x4 acc = {0.f, 0.f, 0.f, 0.f};
#pragma unroll
      for (int ks = 0; ks < 2; ++ks) {
        const bf16x8 af = frag_ld(W2, t * 16 + l15, ks * 32 + quad * 8);
        acc = __builtin_amdgcn_mfma_f32_16x16x32_bf16(af, hfrag[ks], acc, 0, 0, 0);
      }
      const int ob = t * 16 + quad * 4;
#pragma unroll
      for (int r = 0; r < 4; ++r)
        ex[t * 4 + r] = __expf(fmaxf(acc[r] + b2s[ob + r], 0.f));
    }
  }
  // ---- GEMM3: delta = relu(PW2 . hp^T + pb2)  (regs)
  {
    const unsigned short* hp = W1;
    bf16x8 pfrag[2];
#pragma unroll
    for (int ks = 0; ks < 2; ++ks)
      pfrag[ks] = frag_ld(hp, eloc, ks * 32 + quad * 8);
#pragma unroll
    for (int t = 0; t < 4; ++t) {
      f32x4 acc = {0.f, 0.f, 0.f, 0.f};
#pragma unroll
      for (int ks = 0; ks < 2; ++ks) {
        const bf16x8 af = frag_ld(PW2, t * 16 + l15, ks * 32 + quad * 8);
        acc = __builtin_amdgcn_mfma_f32_16x16x32_bf16(af, pfrag[ks], acc, 0, 0, 0);
      }
      const int ob = t * 16 + quad * 4;
#pragma unroll
      for (int r = 0; r < 4; ++r)
        del[t * 4 + r] = fmaxf(acc[r] + pb2s[ob + r], 0.f);
    }
  }
  // v gather before the barrier (global, hides latency)
  float vr[16];
#pragma unroll
  for (int t = 0; t < 4; ++t) {
    const float4 v4 =
        *(const float4*)(vv + (size_t)s_mine * 64 + t * 16 + quad * 4);
    vr[t * 4 + 0] = v4.x;
    vr[t * 4 + 1] = v4.y;
    vr[t * 4 + 2] = v4.z;
    vr[t * 4 + 3] = v4.w;
  }
  __syncthreads();  // B1: all MFMA LDS reads done -> alias region free

  // ---- phase 5: msg/ex -> swizzled stride-65 f32 LDS [o][e]
#pragma unroll
  for (int t = 0; t < 4; ++t) {
#pragma unroll
    for (int r = 0; r < 4; ++r) {
      const int o = t * 16 + quad * 4 + r;
      const int sl = (eloc + o) & 63;
      const float e_ = ex[t * 4 + r];
      msgb[o * 65 + sl] = e_ * (vr[t * 4 + r] + del[t * 4 + r]);
      exb[o * 65 + sl] = e_;
    }
  }
  __syncthreads();  // B2

  // ---- phase 6: segmented reduce over sorted-dst runs, then atomics
  {
    const int c = tid & 63;
    const int r = tid >> 6;
    float am = 0.f, ae = 0.f;
    int cur = -1;
#pragma unroll 1
    for (int t2 = 0; t2 < 16; ++t2) {
      const int el = r * 16 + t2;
      const int d = dsts[el];
      if (d != cur) {
        if (cur >= 0) {
          unsafeAtomicAdd(num + (size_t)cur * 64 + c, am);
          unsafeAtomicAdd(den + (size_t)cur * 64 + c, ae);
        }
        cur = d;
        am = 0.f;
        ae = 0.f;
      }
      if (d >= 0) {
        const int sl = (el + c) & 63;
        am += msgb[c * 65 + sl];
        ae += exb[c * 65 + sl];
      }
    }
    if (cur >= 0) {
      unsafeAtomicAdd(num + (size_t)cur * 64 + c, am);
      unsafeAtomicAdd(den + (size_t)cur * 64 + c, ae);
    }
  }
}

// ---------------------------------------------------------------------------
// Kernel C: out = relu((num/(den+1e-16)) @ W_out.T + b_out)
// ---------------------------------------------------------------------------
__global__ __launch_bounds__(256, 3) void out_proj(
    const float* __restrict__ num, const float* __restrict__ den,
    const float* __restrict__ W_out, const float* __restrict__ b_out,
    float* __restrict__ out) {
  __shared__ __align__(16) float bufY[64 * 64];
  __shared__ __align__(16) float wbuf[64 * 64];
  __shared__ __align__(16) float bias[64];

  const int tid = threadIdx.x;
  const int nb = blockIdx.x * 64;
  const int m0 = (tid & 15) * 4;
  const int o0 = (tid >> 4) * 4;

  {
    const int n = tid >> 2;
    const int kc = (tid & 3) * 16;
    const int gn = nb + n;
#pragma unroll
    for (int u = 0; u < 4; ++u) {
      float4 nm = make_float4(0.f, 0.f, 0.f, 0.f);
      float4 dn = make_float4(1.f, 1.f, 1.f, 1.f);
      if (gn < NN) {
        nm = *(const float4*)(num + (size_t)gn * 64 + kc + 4 * u);
        dn = *(const float4*)(den + (size_t)gn * 64 + kc + 4 * u);
      }
      const int kbi = kc + 4 * u;
      bufY[(kbi + 0) * 64 + n] = nm.x / (dn.x + 1e-16f);
      bufY[(kbi + 1) * 64 + n] = nm.y / (dn.y + 1e-16f);
      bufY[(kbi + 2) * 64 + n] = nm.z / (dn.z + 1e-16f);
      bufY[(kbi + 3) * 64 + n] = nm.w / (dn.w + 1e-16f);
    }
  }
  load_wT(wbuf, W_out, tid);
  if (tid < 64) bias[tid] = b_out[tid];
  __syncthreads();

  float acc[4][4] = {};
  gemm64(bufY, wbuf, m0, o0, acc);
#pragma unroll
  for (int i = 0; i < 4; ++i) {
    const int gn = nb + m0 + i;
    if (gn < NN) {
      float4 r;
      r.x = fmaxf(acc[i][0] + bias[o0 + 0], 0.f);
      r.y = fmaxf(acc[i][1] + bias[o0 + 1], 0.f);
      r.z = fmaxf(acc[i][2] + bias[o0 + 2], 0.f);
      r.w = fmaxf(acc[i][3] + bias[o0 + 3], 0.f);
      *(float4*)(out + (size_t)gn * 64 + o0) = r;
    }
  }
}

extern "C" void kernel_launch(void* const* d_in, const int* in_sizes, int n_in,
                              void* d_out, int out_size, void* d_ws,
                              size_t ws_size, hipStream_t stream) {
  const float* x      = (const float*)d_in[0];
  const float* pos    = (const float*)d_in[1];
  const int*   ei     = (const int*)d_in[2];
  const float* W_in   = (const float*)d_in[3];
  const float* b_in   = (const float*)d_in[4];
  const float* W_out  = (const float*)d_in[5];
  const float* b_out  = (const float*)d_in[6];
  const float* W_lin  = (const float*)d_in[7];
  const float* W_src  = (const float*)d_in[8];
  const float* W_dst  = (const float*)d_in[9];
  const float* pos_w1 = (const float*)d_in[10];
  const float* pos_b1 = (const float*)d_in[11];
  const float* pos_w2 = (const float*)d_in[12];
  const float* pos_b2 = (const float*)d_in[13];
  const float* att_w1 = (const float*)d_in[14];
  const float* att_b1 = (const float*)d_in[15];
  const float* att_w2 = (const float*)d_in[16];
  const float* att_b2 = (const float*)d_in[17];

  float* ws = (float*)d_ws;
  const size_t NC = (size_t)NN * C;
  float* v   = ws;                       // NC f32
  float* num = ws + NC;                  // NC f32
  float* den = ws + 2 * NC;              // NC f32
  unsigned short* kb = (unsigned short*)(ws + 3 * NC);  // NC bf16
  unsigned short* qb = kb + NC;                          // NC bf16
  int* ib   = (int*)(qb + NC);
  int* cnt  = ib;                        // NN
  int* curs = ib + NN;                   // NN
  int2* srt = (int2*)(ib + 2 * NN);      // ET int2

  hipMemsetAsync(num, 0, 2 * NC * sizeof(float), stream);
  hipMemsetAsync(cnt, 0, NN * sizeof(int), stream);

  const dim3 blk(256);
  node_proj<<<dim3((NN + 63) / 64), blk, 0, stream>>>(x, W_in, b_in, W_lin,
                                                      W_src, W_dst, v, kb, qb);
  hist_kernel<<<dim3((ET + 255) / 256), blk, 0, stream>>>(ei, cnt);
  scan_kernel<<<dim3(1), dim3(1024), 0, stream>>>(cnt, curs);
  scatter_kernel<<<dim3((ET + 255) / 256), blk, 0, stream>>>(ei, curs, srt);
  edge_pass<<<dim3((ET + 63) / 64), blk, 0, stream>>>(
      srt, pos, v, kb, qb, att_w1, att_b1, att_w2, att_b2, pos_w1, pos_b1,
      pos_w2, pos_b2, num, den);
  out_proj<<<dim3((NN + 63) / 64), blk, 0, stream>>>(num, den, W_out, b_out,
                                                     (float*)d_out);
}

// Round 5
// 362.935 us; speedup vs baseline: 4.3702x; 1.2680x over previous
//
#include <hip/hip_runtime.h>
#include <math.h>

#define NN 50000
#define EE 800000
#define ET (EE + NN)   // 850000 edges incl. self-loops
#define C  64
#define NBLK 49        // ceil(NN/1024) scan blocks

typedef __attribute__((ext_vector_type(8))) _Float16 f16x8;
typedef __attribute__((ext_vector_type(4))) _Float16 f16x4;
typedef __attribute__((ext_vector_type(2))) _Float16 f16x2;
typedef __attribute__((ext_vector_type(4))) float f32x4;

__device__ __forceinline__ f16x2 pk2(float a, float b) {
  return __builtin_bit_cast(f16x2, __builtin_amdgcn_cvt_pkrtz(a, b));
}
__device__ __forceinline__ f16x4 pk4(float a, float b, float c, float d) {
  return __builtin_shufflevector(pk2(a, b), pk2(c, d), 0, 1, 2, 3);
}

// f16 LDS row read: 8 consecutive k at 16B alignment (stride 72 halves)
__device__ __forceinline__ f16x8 frag_ldh(const _Float16* base, int row,
                                          int kofs) {
  return *(const f16x8*)(base + row * 72 + kofs);
}

// fp32 64x64 row-major weight -> f16 LDS, stride 72
__device__ __forceinline__ void load_whf(_Float16* __restrict__ dst,
                                         const float* __restrict__ W, int tid) {
  const int o = tid >> 2;
  const int kc = (tid & 3) * 16;
  const float4* src = (const float4*)(W + o * 64 + kc);
  f16x4* d = (f16x4*)(dst + o * 72 + kc);
#pragma unroll
  for (int u = 0; u < 4; ++u) {
    const float4 w = src[u];
    d[u] = pk4(w.x, w.y, w.z, w.w);
  }
}

// ---------------------------------------------------------------------------
// fp32 GEMM microkernel (node/out projections)
// ---------------------------------------------------------------------------
__device__ __forceinline__ void gemm64(const float* __restrict__ AT,
                                       const float* __restrict__ WT,
                                       int m0, int o0, float acc[4][4]) {
#pragma unroll 8
  for (int k = 0; k < 64; ++k) {
    const float4 a = *(const float4*)(AT + k * 64 + m0);
    const float4 w = *(const float4*)(WT + k * 64 + o0);
    const float av[4] = {a.x, a.y, a.z, a.w};
    const float wv[4] = {w.x, w.y, w.z, w.w};
#pragma unroll
    for (int i = 0; i < 4; ++i)
#pragma unroll
      for (int j = 0; j < 4; ++j) acc[i][j] = fmaf(av[i], wv[j], acc[i][j]);
  }
}

__device__ __forceinline__ void load_wT(float* __restrict__ dst,
                                        const float* __restrict__ W, int tid) {
  const int o = tid >> 2;
  const int kc = (tid & 3) * 16;
  const float4* src = (const float4*)(W + o * 64 + kc);
#pragma unroll
  for (int u = 0; u < 4; ++u) {
    const float4 wv = src[u];
    const int kb = kc + 4 * u;
    dst[(kb + 0) * 64 + o] = wv.x;
    dst[(kb + 1) * 64 + o] = wv.y;
    dst[(kb + 2) * 64 + o] = wv.z;
    dst[(kb + 3) * 64 + o] = wv.w;
  }
}

// ---------------------------------------------------------------------------
// Hierarchical exclusive scan of cnt[NN] -> curs[NN]
// ---------------------------------------------------------------------------
__global__ __launch_bounds__(256) void scan_partial(const int* __restrict__ cnt,
                                                    int* __restrict__ bsum) {
  __shared__ int ws[4];
  const int t = threadIdx.x;
  const int base = blockIdx.x * 1024 + t * 4;
  int s = 0;
  if (base + 3 < NN) {
    const int4 v = *(const int4*)(cnt + base);
    s = v.x + v.y + v.z + v.w;
  } else {
#pragma unroll
    for (int i = 0; i < 4; ++i)
      if (base + i < NN) s += cnt[base + i];
  }
#pragma unroll
  for (int off = 32; off; off >>= 1) s += __shfl_down(s, off, 64);
  if ((t & 63) == 0) ws[t >> 6] = s;
  __syncthreads();
  if (t == 0) bsum[blockIdx.x] = ws[0] + ws[1] + ws[2] + ws[3];
}

__global__ __launch_bounds__(64) void scan_mid(const int* __restrict__ bsum,
                                               int* __restrict__ boff) {
  const int t = threadIdx.x;
  const int mine = (t < NBLK) ? bsum[t] : 0;
  int v = mine;
#pragma unroll
  for (int off = 1; off < 64; off <<= 1) {
    const int u = __shfl_up(v, off, 64);
    if (t >= off) v += u;
  }
  if (t < NBLK) boff[t] = v - mine;  // exclusive
}

__global__ __launch_bounds__(256) void scan_final(const int* __restrict__ cnt,
                                                  const int* __restrict__ boff,
                                                  int* __restrict__ curs) {
  __shared__ int tsum[256];
  const int t = threadIdx.x;
  const int base = blockIdx.x * 1024 + t * 4;
  int v[4] = {0, 0, 0, 0};
  if (base + 3 < NN) {
    const int4 x = *(const int4*)(cnt + base);
    v[0] = x.x; v[1] = x.y; v[2] = x.z; v[3] = x.w;
  } else {
#pragma unroll
    for (int i = 0; i < 4; ++i)
      if (base + i < NN) v[i] = cnt[base + i];
  }
  const int s = v[0] + v[1] + v[2] + v[3];
  tsum[t] = s;
  __syncthreads();
  for (int off = 1; off < 256; off <<= 1) {
    const int u = (t >= off) ? tsum[t - off] : 0;
    __syncthreads();
    tsum[t] += u;
    __syncthreads();
  }
  int ex = boff[blockIdx.x] + tsum[t] - s;
#pragma unroll
  for (int i = 0; i < 4; ++i) {
    if (base + i < NN) curs[base + i] = ex;
    ex += v[i];
  }
}

__global__ void scatter_kernel(const int* __restrict__ ei,
                               int* __restrict__ curs, int2* __restrict__ srt) {
  const int e = blockIdx.x * 256 + threadIdx.x;
  if (e >= ET) return;
  int s, d;
  if (e < EE) {
    s = ei[e];
    d = ei[EE + e];
  } else {
    s = e - EE;
    d = s;
  }
  const int p = atomicAdd(&curs[d], 1);
  srt[p] = make_int2(s, d);
}

// ---------------------------------------------------------------------------
// Kernel A: fused histogram + node projections.
// h = relu(x@W_in.T+b); v = h@W_lin.T (f32); k/q = h@W_{src,dst}.T (f16)
// ---------------------------------------------------------------------------
__global__ __launch_bounds__(256, 3) void node_proj(
    const float* __restrict__ x, const float* __restrict__ W_in,
    const float* __restrict__ b_in, const float* __restrict__ W_lin,
    const float* __restrict__ W_src, const float* __restrict__ W_dst,
    const int* __restrict__ ei, int* __restrict__ cnt, float* __restrict__ v,
    _Float16* __restrict__ kh, _Float16* __restrict__ qh) {
  __shared__ __align__(16) float bufX[64 * 64];
  __shared__ __align__(16) float bufH[64 * 64];
  __shared__ __align__(16) float wbuf[64 * 64];
  __shared__ __align__(16) float bias[64];

  const int tid = threadIdx.x;
  const int nb = blockIdx.x * 64;
  const int m0 = (tid & 15) * 4;
  const int o0 = (tid >> 4) * 4;

  // fire-and-forget histogram (no-return atomics don't stall the GEMM)
  {
    const int stride = gridDim.x * 256;
    for (int e = blockIdx.x * 256 + tid; e < ET; e += stride) {
      const int d = (e < EE) ? ei[EE + e] : (e - EE);
      atomicAdd(&cnt[d], 1);
    }
  }

  {
    const int n = tid >> 2;
    const int kc = (tid & 3) * 16;
    const int gn = nb + n;
#pragma unroll
    for (int u = 0; u < 4; ++u) {
      float4 xv = make_float4(0.f, 0.f, 0.f, 0.f);
      if (gn < NN) xv = *(const float4*)(x + (size_t)gn * 64 + kc + 4 * u);
      const int kbi = kc + 4 * u;
      bufX[(kbi + 0) * 64 + n] = xv.x;
      bufX[(kbi + 1) * 64 + n] = xv.y;
      bufX[(kbi + 2) * 64 + n] = xv.z;
      bufX[(kbi + 3) * 64 + n] = xv.w;
    }
  }
  load_wT(wbuf, W_in, tid);
  if (tid < 64) bias[tid] = b_in[tid];
  __syncthreads();

  float acc[4][4] = {};
  gemm64(bufX, wbuf, m0, o0, acc);
#pragma unroll
  for (int i = 0; i < 4; ++i)
#pragma unroll
    for (int j = 0; j < 4; ++j) {
      const float h = fmaxf(acc[i][j] + bias[o0 + j], 0.f);
      bufH[(o0 + j) * 64 + (m0 + i)] = h;
    }
  __syncthreads();

  const float* Ws[3] = {W_lin, W_src, W_dst};
#pragma unroll 1
  for (int p = 0; p < 3; ++p) {
    load_wT(wbuf, Ws[p], tid);
    __syncthreads();
    float a2[4][4] = {};
    gemm64(bufH, wbuf, m0, o0, a2);
#pragma unroll
    for (int i = 0; i < 4; ++i) {
      const int gn = nb + m0 + i;
      if (gn < NN) {
        if (p == 0) {
          const float4 r = make_float4(a2[i][0], a2[i][1], a2[i][2], a2[i][3]);
          *(float4*)(v + (size_t)gn * 64 + o0) = r;
        } else {
          _Float16* dst = (p == 1) ? kh : qh;
          *(f16x4*)(dst + (size_t)gn * 64 + o0) =
              pk4(a2[i][0], a2[i][1], a2[i][2], a2[i][3]);
        }
      }
    }
    __syncthreads();
  }
}

// ---------------------------------------------------------------------------
// Kernel B: MFMA (f16) edge pass. Wave w owns edges [w*16, w*16+16).
// ---------------------------------------------------------------------------
__global__ __launch_bounds__(256, 4) void edge_pass(
    const int2* __restrict__ srt, const float* __restrict__ pos,
    const float* __restrict__ vv, const _Float16* __restrict__ kh,
    const _Float16* __restrict__ qh, const float* __restrict__ att_w1,
    const float* __restrict__ att_b1, const float* __restrict__ att_w2,
    const float* __restrict__ att_b2, const float* __restrict__ pos_w1,
    const float* __restrict__ pos_b1, const float* __restrict__ pos_w2,
    const float* __restrict__ pos_b2, float* __restrict__ num,
    float* __restrict__ den) {
  // 36864B: W1(->hp) | W2 | PW2 | h1, each 64 rows x stride 72 f16.
  // After B1 reused as pairb (float2[64*65] = 33280B).
  __shared__ __align__(16) _Float16 smem[18432];
  __shared__ __align__(16) float dpT[3 * 64];
  __shared__ __align__(16) float posw1T[3 * 64];
  __shared__ float b1s[64], b2s[64], pb1s[64], pb2s[64];
  __shared__ int srcs[64], dsts[64];

  _Float16* W1  = smem;          // later: hp
  _Float16* W2  = smem + 4608;
  _Float16* PW2 = smem + 9216;
  _Float16* h1  = smem + 13824;
  float2* pairb = (float2*)smem;  // (msg, ex) interleaved

  const int tid = threadIdx.x;
  const int eb = blockIdx.x * 64;
  const int l15 = tid & 15;
  const int quad = (tid >> 4) & 3;
  const int wband = tid >> 6;
  const int eloc = wband * 16 + l15;  // this lane's edge (block-local)

  // ---- phase 0a: per-lane B-frag: ad = q[dst]-k[src] (f16, v_pk_add)
  int s_mine, d_mine;
  f16x8 bfrag[2];
  {
    const int e = eb + eloc;
    int2 sd = make_int2(0, 0);
    if (e < ET) sd = srt[e];
    s_mine = sd.x;
    d_mine = sd.y;
#pragma unroll
    for (int ks = 0; ks < 2; ++ks) {
      const f16x8 qv =
          *(const f16x8*)(qh + (size_t)d_mine * 64 + ks * 32 + quad * 8);
      const f16x8 kv =
          *(const f16x8*)(kh + (size_t)s_mine * 64 + ks * 32 + quad * 8);
      bfrag[ks] = qv - kv;
    }
  }

  // ---- phase 0b: stage weights (f16), biases, indices, dp
  load_whf(W1, att_w1, tid);
  load_whf(W2, att_w2, tid);
  load_whf(PW2, pos_w2, tid);
  if (tid < 64) {
    b1s[tid] = att_b1[tid];
    b2s[tid] = att_b2[tid];
    pb1s[tid] = pos_b1[tid];
    pb2s[tid] = pos_b2[tid];
    posw1T[0 * 64 + tid] = pos_w1[tid * 3 + 0];
    posw1T[1 * 64 + tid] = pos_w1[tid * 3 + 1];
    posw1T[2 * 64 + tid] = pos_w1[tid * 3 + 2];
  }
  if ((tid & 3) == 0) {
    const int el = tid >> 2;
    const int e = eb + el;
    int s = 0, d = -1;
    if (e < ET) {
      const int2 sd = srt[e];
      s = sd.x;
      d = sd.y;
    }
    srcs[el] = s;
    dsts[el] = d;
    const int d0 = (d < 0) ? 0 : d;
    dpT[0 * 64 + el] = pos[(size_t)d0 * 3 + 0] - pos[(size_t)s * 3 + 0];
    dpT[1 * 64 + el] = pos[(size_t)d0 * 3 + 1] - pos[(size_t)s * 3 + 1];
    dpT[2 * 64 + el] = pos[(size_t)d0 * 3 + 2] - pos[(size_t)s * 3 + 2];
  }
  __syncthreads();  // B0

  // ---- GEMM1: h1[h][e] = relu(W1 . ad^T + b1) -> h1 rows [e][h] f16
#pragma unroll
  for (int t = 0; t < 4; ++t) {
    f32x4 acc = {0.f, 0.f, 0.f, 0.f};
#pragma unroll
    for (int ks = 0; ks < 2; ++ks) {
      const f16x8 af = frag_ldh(W1, t * 16 + l15, ks * 32 + quad * 8);
      acc = __builtin_amdgcn_mfma_f32_16x16x32_f16(af, bfrag[ks], acc, 0, 0, 0);
    }
    const int hb = t * 16 + quad * 4;
    *(f16x4*)(h1 + eloc * 72 + hb) =
        pk4(fmaxf(acc[0] + b1s[hb + 0], 0.f), fmaxf(acc[1] + b1s[hb + 1], 0.f),
            fmaxf(acc[2] + b1s[hb + 2], 0.f), fmaxf(acc[3] + b1s[hb + 3], 0.f));
  }
  __syncthreads();  // B0.5: W1 reads done -> region becomes hp

  // ---- phase 2: hp = relu(dp @ pos_w1.T + pb1) (k=3, VALU) -> hp rows f16
  // Mapping swapped vs edges-from-low-bits: edges from tid>>4 (bank floor).
  {
    const int m0 = (tid >> 4) * 4;  // edge
    const int o0 = (tid & 15) * 4;  // hidden
    float acc[4][4] = {};
#pragma unroll
    for (int k = 0; k < 3; ++k) {
      const float4 a = *(const float4*)(dpT + k * 64 + m0);
      const float4 w = *(const float4*)(posw1T + k * 64 + o0);
      const float av[4] = {a.x, a.y, a.z, a.w};
      const float wv[4] = {w.x, w.y, w.z, w.w};
#pragma unroll
      for (int i = 0; i < 4; ++i)
#pragma unroll
        for (int j = 0; j < 4; ++j) acc[i][j] = fmaf(av[i], wv[j], acc[i][j]);
    }
    _Float16* hp = W1;
#pragma unroll
    for (int i = 0; i < 4; ++i) {
      *(f16x4*)(hp + (m0 + i) * 72 + o0) =
          pk4(fmaxf(acc[i][0] + pb1s[o0 + 0], 0.f),
              fmaxf(acc[i][1] + pb1s[o0 + 1], 0.f),
              fmaxf(acc[i][2] + pb1s[o0 + 2], 0.f),
              fmaxf(acc[i][3] + pb1s[o0 + 3], 0.f));
    }
  }
  __syncthreads();  // B0.75: hp visible

  // ---- GEMM2: alpha = relu(W2 . h1^T + b2); ex = exp(alpha)  (regs)
  float ex[16], del[16];
  {
    f16x8 hfrag[2];
#pragma unroll
    for (int ks = 0; ks < 2; ++ks)
      hfrag[ks] = frag_ldh(h1, eloc, ks * 32 + quad * 8);
#pragma unroll
    for (int t = 0; t < 4; ++t) {
      f32x4 acc = {0.f, 0.f, 0.f, 0.f};
#pragma unroll
      for (int ks = 0; ks < 2; ++ks) {
        const f16x8 af = frag_ldh(W2, t * 16 + l15, ks * 32 + quad * 8);
        acc = __builtin_amdgcn_mfma_f32_16x16x32_f16(af, hfrag[ks], acc, 0, 0, 0);
      }
      const int ob = t * 16 + quad * 4;
#pragma unroll
      for (int r = 0; r < 4; ++r)
        ex[t * 4 + r] = __expf(fmaxf(acc[r] + b2s[ob + r], 0.f));
    }
  }
  // ---- GEMM3: delta = relu(PW2 . hp^T + pb2)  (regs)
  {
    const _Float16* hp = W1;
    f16x8 pfrag[2];
#pragma unroll
    for (int ks = 0; ks < 2; ++ks)
      pfrag[ks] = frag_ldh(hp, eloc, ks * 32 + quad * 8);
#pragma unroll
    for (int t = 0; t < 4; ++t) {
      f32x4 acc = {0.f, 0.f, 0.f, 0.f};
#pragma unroll
      for (int ks = 0; ks < 2; ++ks) {
        const f16x8 af = frag_ldh(PW2, t * 16 + l15, ks * 32 + quad * 8);
        acc = __builtin_amdgcn_mfma_f32_16x16x32_f16(af, pfrag[ks], acc, 0, 0, 0);
      }
      const int ob = t * 16 + quad * 4;
#pragma unroll
      for (int r = 0; r < 4; ++r)
        del[t * 4 + r] = fmaxf(acc[r] + pb2s[ob + r], 0.f);
    }
  }
  // v gather before the barrier (global, hides latency)
  float vr[16];
#pragma unroll
  for (int t = 0; t < 4; ++t) {
    const float4 v4 =
        *(const float4*)(vv + (size_t)s_mine * 64 + t * 16 + quad * 4);
    vr[t * 4 + 0] = v4.x;
    vr[t * 4 + 1] = v4.y;
    vr[t * 4 + 2] = v4.z;
    vr[t * 4 + 3] = v4.w;
  }
  __syncthreads();  // B1: all LDS reads done -> alias region free

  // ---- phase 5: (msg, ex) -> pairb, slot = (e + 2o) & 63 (bank floor)
#pragma unroll
  for (int t = 0; t < 4; ++t) {
#pragma unroll
    for (int r = 0; r < 4; ++r) {
      const int o = t * 16 + quad * 4 + r;
      const int sl = (eloc + 2 * o) & 63;
      const float e_ = ex[t * 4 + r];
      pairb[o * 65 + sl] = make_float2(e_ * (vr[t * 4 + r] + del[t * 4 + r]), e_);
    }
  }
  __syncthreads();  // B2

  // ---- phase 6: segmented reduce over sorted-dst runs, then atomics
  {
    const int c = tid & 63;
    const int r = tid >> 6;
    float am = 0.f, ae = 0.f;
    int cur = -1;
#pragma unroll 1
    for (int t2 = 0; t2 < 16; ++t2) {
      const int el = r * 16 + t2;
      const int d = dsts[el];
      if (d != cur) {
        if (cur >= 0) {
          unsafeAtomicAdd(num + (size_t)cur * 64 + c, am);
          unsafeAtomicAdd(den + (size_t)cur * 64 + c, ae);
        }
        cur = d;
        am = 0.f;
        ae = 0.f;
      }
      if (d >= 0) {
        const float2 pe = pairb[c * 65 + ((el + 2 * c) & 63)];
        am += pe.x;
        ae += pe.y;
      }
    }
    if (cur >= 0) {
      unsafeAtomicAdd(num + (size_t)cur * 64 + c, am);
      unsafeAtomicAdd(den + (size_t)cur * 64 + c, ae);
    }
  }
}

// ---------------------------------------------------------------------------
// Kernel C: out = relu((num/(den+1e-16)) @ W_out.T + b_out)
// ---------------------------------------------------------------------------
__global__ __launch_bounds__(256, 3) void out_proj(
    const float* __restrict__ num, const float* __restrict__ den,
    const float* __restrict__ W_out, const float* __restrict__ b_out,
    float* __restrict__ out) {
  __shared__ __align__(16) float bufY[64 * 64];
  __shared__ __align__(16) float wbuf[64 * 64];
  __shared__ __align__(16) float bias[64];

  const int tid = threadIdx.x;
  const int nb = blockIdx.x * 64;
  const int m0 = (tid & 15) * 4;
  const int o0 = (tid >> 4) * 4;

  {
    const int n = tid >> 2;
    const int kc = (tid & 3) * 16;
    const int gn = nb + n;
#pragma unroll
    for (int u = 0; u < 4; ++u) {
      float4 nm = make_float4(0.f, 0.f, 0.f, 0.f);
      float4 dn = make_float4(1.f, 1.f, 1.f, 1.f);
      if (gn < NN) {
        nm = *(const float4*)(num + (size_t)gn * 64 + kc + 4 * u);
        dn = *(const float4*)(den + (size_t)gn * 64 + kc + 4 * u);
      }
      const int kbi = kc + 4 * u;
      bufY[(kbi + 0) * 64 + n] = nm.x / (dn.x + 1e-16f);
      bufY[(kbi + 1) * 64 + n] = nm.y / (dn.y + 1e-16f);
      bufY[(kbi + 2) * 64 + n] = nm.z / (dn.z + 1e-16f);
      bufY[(kbi + 3) * 64 + n] = nm.w / (dn.w + 1e-16f);
    }
  }
  load_wT(wbuf, W_out, tid);
  if (tid < 64) bias[tid] = b_out[tid];
  __syncthreads();

  float acc[4][4] = {};
  gemm64(bufY, wbuf, m0, o0, acc);
#pragma unroll
  for (int i = 0; i < 4; ++i) {
    const int gn = nb + m0 + i;
    if (gn < NN) {
      float4 r;
      r.x = fmaxf(acc[i][0] + bias[o0 + 0], 0.f);
      r.y = fmaxf(acc[i][1] + bias[o0 + 1], 0.f);
      r.z = fmaxf(acc[i][2] + bias[o0 + 2], 0.f);
      r.w = fmaxf(acc[i][3] + bias[o0 + 3], 0.f);
      *(float4*)(out + (size_t)gn * 64 + o0) = r;
    }
  }
}

extern "C" void kernel_launch(void* const* d_in, const int* in_sizes, int n_in,
                              void* d_out, int out_size, void* d_ws,
                              size_t ws_size, hipStream_t stream) {
  const float* x      = (const float*)d_in[0];
  const float* pos    = (const float*)d_in[1];
  const int*   ei     = (const int*)d_in[2];
  const float* W_in   = (const float*)d_in[3];
  const float* b_in   = (const float*)d_in[4];
  const float* W_out  = (const float*)d_in[5];
  const float* b_out  = (const float*)d_in[6];
  const float* W_lin  = (const float*)d_in[7];
  const float* W_src  = (const float*)d_in[8];
  const float* W_dst  = (const float*)d_in[9];
  const float* pos_w1 = (const float*)d_in[10];
  const float* pos_b1 = (const float*)d_in[11];
  const float* pos_w2 = (const float*)d_in[12];
  const float* pos_b2 = (const float*)d_in[13];
  const float* att_w1 = (const float*)d_in[14];
  const float* att_b1 = (const float*)d_in[15];
  const float* att_w2 = (const float*)d_in[16];
  const float* att_b2 = (const float*)d_in[17];

  float* ws = (float*)d_ws;
  const size_t NC = (size_t)NN * C;
  float* v   = ws;                       // NC f32
  float* num = ws + NC;                  // NC f32
  float* den = ws + 2 * NC;              // NC f32
  _Float16* kh = (_Float16*)(ws + 3 * NC);  // NC f16
  _Float16* qh = kh + NC;                    // NC f16
  int* ib    = (int*)(qh + NC);
  int* cnt   = ib;                       // NN
  int* curs  = ib + NN;                  // NN
  int* bsum  = ib + 2 * NN;              // NBLK
  int* boff  = bsum + NBLK;              // NBLK
  int2* srt  = (int2*)(((uintptr_t)(boff + NBLK) + 15) & ~(uintptr_t)15);

  hipMemsetAsync(num, 0, 2 * NC * sizeof(float), stream);
  hipMemsetAsync(cnt, 0, NN * sizeof(int), stream);

  const dim3 blk(256);
  node_proj<<<dim3((NN + 63) / 64), blk, 0, stream>>>(
      x, W_in, b_in, W_lin, W_src, W_dst, ei, cnt, v, kh, qh);
  scan_partial<<<dim3(NBLK), blk, 0, stream>>>(cnt, bsum);
  scan_mid<<<dim3(1), dim3(64), 0, stream>>>(bsum, boff);
  scan_final<<<dim3(NBLK), blk, 0, stream>>>(cnt, boff, curs);
  scatter_kernel<<<dim3((ET + 255) / 256), blk, 0, stream>>>(ei, curs, srt);
  edge_pass<<<dim3((ET + 63) / 64), blk, 0, stream>>>(
      srt, pos, v, kh, qh, att_w1, att_b1, att_w2, att_b2, pos_w1, pos_b1,
      pos_w2, pos_b2, num, den);
  out_proj<<<dim3((NN + 63) / 64), blk, 0, stream>>>(num, den, W_out, b_out,
                                                     (float*)d_out);
}

// Round 6
// 344.470 us; speedup vs baseline: 4.6045x; 1.0536x over previous
//
#include <hip/hip_runtime.h>
#include <math.h>

#define NN 50000
#define EE 800000
#define ET (EE + NN)   // 850000 edges incl. self-loops
#define C  64
#define NBLK 49        // ceil(NN/1024) scan blocks

typedef __attribute__((ext_vector_type(8))) _Float16 f16x8;
typedef __attribute__((ext_vector_type(4))) _Float16 f16x4;
typedef __attribute__((ext_vector_type(2))) _Float16 f16x2;
typedef __attribute__((ext_vector_type(4))) float f32x4;

__device__ __forceinline__ f16x2 pk2(float a, float b) {
  return __builtin_bit_cast(f16x2, __builtin_amdgcn_cvt_pkrtz(a, b));
}
__device__ __forceinline__ f16x4 pk4(float a, float b, float c, float d) {
  return __builtin_shufflevector(pk2(a, b), pk2(c, d), 0, 1, 2, 3);
}

// f16 LDS row read: 8 consecutive k at 16B alignment (stride 72 halves)
__device__ __forceinline__ f16x8 frag_ldh(const _Float16* base, int row,
                                          int kofs) {
  return *(const f16x8*)(base + row * 72 + kofs);
}

// fp32 64x64 row-major weight -> f16 LDS, stride 72
__device__ __forceinline__ void load_whf(_Float16* __restrict__ dst,
                                         const float* __restrict__ W, int tid) {
  const int o = tid >> 2;
  const int kc = (tid & 3) * 16;
  const float4* src = (const float4*)(W + o * 64 + kc);
  f16x4* d = (f16x4*)(dst + o * 72 + kc);
#pragma unroll
  for (int u = 0; u < 4; ++u) {
    const float4 w = src[u];
    d[u] = pk4(w.x, w.y, w.z, w.w);
  }
}

// ---------------------------------------------------------------------------
// fp32 GEMM microkernel (node/out projections)
// ---------------------------------------------------------------------------
__device__ __forceinline__ void gemm64(const float* __restrict__ AT,
                                       const float* __restrict__ WT,
                                       int m0, int o0, float acc[4][4]) {
#pragma unroll 8
  for (int k = 0; k < 64; ++k) {
    const float4 a = *(const float4*)(AT + k * 64 + m0);
    const float4 w = *(const float4*)(WT + k * 64 + o0);
    const float av[4] = {a.x, a.y, a.z, a.w};
    const float wv[4] = {w.x, w.y, w.z, w.w};
#pragma unroll
    for (int i = 0; i < 4; ++i)
#pragma unroll
      for (int j = 0; j < 4; ++j) acc[i][j] = fmaf(av[i], wv[j], acc[i][j]);
  }
}

__device__ __forceinline__ void load_wT(float* __restrict__ dst,
                                        const float* __restrict__ W, int tid) {
  const int o = tid >> 2;
  const int kc = (tid & 3) * 16;
  const float4* src = (const float4*)(W + o * 64 + kc);
#pragma unroll
  for (int u = 0; u < 4; ++u) {
    const float4 wv = src[u];
    const int kb = kc + 4 * u;
    dst[(kb + 0) * 64 + o] = wv.x;
    dst[(kb + 1) * 64 + o] = wv.y;
    dst[(kb + 2) * 64 + o] = wv.z;
    dst[(kb + 3) * 64 + o] = wv.w;
  }
}

// ---------------------------------------------------------------------------
// Scan: per-block partial sums, then final (block offsets re-derived in-block)
// ---------------------------------------------------------------------------
__global__ __launch_bounds__(256) void scan_partial(const int* __restrict__ cnt,
                                                    int* __restrict__ bsum) {
  __shared__ int ws[4];
  const int t = threadIdx.x;
  const int base = blockIdx.x * 1024 + t * 4;
  int s = 0;
  if (base + 3 < NN) {
    const int4 v = *(const int4*)(cnt + base);
    s = v.x + v.y + v.z + v.w;
  } else {
#pragma unroll
    for (int i = 0; i < 4; ++i)
      if (base + i < NN) s += cnt[base + i];
  }
#pragma unroll
  for (int off = 32; off; off >>= 1) s += __shfl_down(s, off, 64);
  if ((t & 63) == 0) ws[t >> 6] = s;
  __syncthreads();
  if (t == 0) bsum[blockIdx.x] = ws[0] + ws[1] + ws[2] + ws[3];
}

__global__ __launch_bounds__(256) void scan_final(const int* __restrict__ cnt,
                                                  const int* __restrict__ bsum,
                                                  int* __restrict__ curs) {
  __shared__ int tsum[256];
  __shared__ int sblk[64];
  const int t = threadIdx.x;
  // first wave: exclusive scan of the 49 block sums (redundant per block, cheap)
  if (t < 64) {
    const int mine = (t < NBLK) ? bsum[t] : 0;
    int v = mine;
#pragma unroll
    for (int off = 1; off < 64; off <<= 1) {
      const int u = __shfl_up(v, off, 64);
      if (t >= off) v += u;
    }
    sblk[t] = v - mine;
  }
  const int base = blockIdx.x * 1024 + t * 4;
  int v[4] = {0, 0, 0, 0};
  if (base + 3 < NN) {
    const int4 x = *(const int4*)(cnt + base);
    v[0] = x.x; v[1] = x.y; v[2] = x.z; v[3] = x.w;
  } else {
#pragma unroll
    for (int i = 0; i < 4; ++i)
      if (base + i < NN) v[i] = cnt[base + i];
  }
  const int s = v[0] + v[1] + v[2] + v[3];
  tsum[t] = s;
  __syncthreads();
  for (int off = 1; off < 256; off <<= 1) {
    const int u = (t >= off) ? tsum[t - off] : 0;
    __syncthreads();
    tsum[t] += u;
    __syncthreads();
  }
  int ex = sblk[blockIdx.x] + tsum[t] - s;
#pragma unroll
  for (int i = 0; i < 4; ++i) {
    if (base + i < NN) curs[base + i] = ex;
    ex += v[i];
  }
}

__global__ void scatter_kernel(const int* __restrict__ ei,
                               int* __restrict__ curs, int2* __restrict__ srt) {
  const int e = blockIdx.x * 256 + threadIdx.x;
  if (e >= ET) return;
  int s, d;
  if (e < EE) {
    s = ei[e];
    d = ei[EE + e];
  } else {
    s = e - EE;
    d = s;
  }
  const int p = atomicAdd(&curs[d], 1);
  srt[p] = make_int2(s, d);
}

// ---------------------------------------------------------------------------
// Kernel A: fused histogram + node projections.
// h = relu(x@W_in.T+b); v = h@W_lin.T (f32); k/q = h@W_{src,dst}.T (f16)
// ---------------------------------------------------------------------------
__global__ __launch_bounds__(256, 3) void node_proj(
    const float* __restrict__ x, const float* __restrict__ W_in,
    const float* __restrict__ b_in, const float* __restrict__ W_lin,
    const float* __restrict__ W_src, const float* __restrict__ W_dst,
    const int* __restrict__ ei, int* __restrict__ cnt, float* __restrict__ v,
    _Float16* __restrict__ kh, _Float16* __restrict__ qh) {
  __shared__ __align__(16) float bufX[64 * 64];
  __shared__ __align__(16) float bufH[64 * 64];
  __shared__ __align__(16) float wbuf[64 * 64];
  __shared__ __align__(16) float bias[64];

  const int tid = threadIdx.x;
  const int nb = blockIdx.x * 64;
  const int m0 = (tid & 15) * 4;
  const int o0 = (tid >> 4) * 4;

  // fire-and-forget histogram (no-return atomics don't stall the GEMM)
  {
    const int stride = gridDim.x * 256;
    for (int e = blockIdx.x * 256 + tid; e < ET; e += stride) {
      const int d = (e < EE) ? ei[EE + e] : (e - EE);
      atomicAdd(&cnt[d], 1);
    }
  }

  {
    const int n = tid >> 2;
    const int kc = (tid & 3) * 16;
    const int gn = nb + n;
#pragma unroll
    for (int u = 0; u < 4; ++u) {
      float4 xv = make_float4(0.f, 0.f, 0.f, 0.f);
      if (gn < NN) xv = *(const float4*)(x + (size_t)gn * 64 + kc + 4 * u);
      const int kbi = kc + 4 * u;
      bufX[(kbi + 0) * 64 + n] = xv.x;
      bufX[(kbi + 1) * 64 + n] = xv.y;
      bufX[(kbi + 2) * 64 + n] = xv.z;
      bufX[(kbi + 3) * 64 + n] = xv.w;
    }
  }
  load_wT(wbuf, W_in, tid);
  if (tid < 64) bias[tid] = b_in[tid];
  __syncthreads();

  float acc[4][4] = {};
  gemm64(bufX, wbuf, m0, o0, acc);
#pragma unroll
  for (int i = 0; i < 4; ++i)
#pragma unroll
    for (int j = 0; j < 4; ++j) {
      const float h = fmaxf(acc[i][j] + bias[o0 + j], 0.f);
      bufH[(o0 + j) * 64 + (m0 + i)] = h;
    }
  __syncthreads();

  const float* Ws[3] = {W_lin, W_src, W_dst};
#pragma unroll 1
  for (int p = 0; p < 3; ++p) {
    load_wT(wbuf, Ws[p], tid);
    __syncthreads();
    float a2[4][4] = {};
    gemm64(bufH, wbuf, m0, o0, a2);
#pragma unroll
    for (int i = 0; i < 4; ++i) {
      const int gn = nb + m0 + i;
      if (gn < NN) {
        if (p == 0) {
          const float4 r = make_float4(a2[i][0], a2[i][1], a2[i][2], a2[i][3]);
          *(float4*)(v + (size_t)gn * 64 + o0) = r;
        } else {
          _Float16* dst = (p == 1) ? kh : qh;
          *(f16x4*)(dst + (size_t)gn * 64 + o0) =
              pk4(a2[i][0], a2[i][1], a2[i][2], a2[i][3]);
        }
      }
    }
    __syncthreads();
  }
}

// ---------------------------------------------------------------------------
// Kernel B: MFMA (f16) edge pass, 4 barriers. Wave w owns edges [w*16,w*16+16).
// hp (pos-MLP hidden) computed per-lane in REGISTERS (no LDS round trip).
// ---------------------------------------------------------------------------
__global__ __launch_bounds__(256, 4) void edge_pass(
    const int2* __restrict__ srt, const float* __restrict__ pos,
    const float* __restrict__ vv, const _Float16* __restrict__ kh,
    const _Float16* __restrict__ qh, const float* __restrict__ att_w1,
    const float* __restrict__ att_b1, const float* __restrict__ att_w2,
    const float* __restrict__ att_b2, const float* __restrict__ pos_w1,
    const float* __restrict__ pos_b1, const float* __restrict__ pos_w2,
    const float* __restrict__ pos_b2, float* __restrict__ num,
    float* __restrict__ den) {
  // 36864B: W1 | W2 | PW2 | h1, each 64 rows x stride 72 f16.
  // After B2 reused as pairb (float2[64*65] = 33280B).
  __shared__ __align__(16) _Float16 smem[18432];
  __shared__ __align__(16) float posw1T[3 * 64];
  __shared__ float b1s[64], b2s[64], pb1s[64], pb2s[64];
  __shared__ int dsts[64];

  _Float16* W1  = smem;
  _Float16* W2  = smem + 4608;
  _Float16* PW2 = smem + 9216;
  _Float16* h1  = smem + 13824;
  float2* pairb = (float2*)smem;  // (msg, ex) interleaved

  const int tid = threadIdx.x;
  const int eb = blockIdx.x * 64;
  const int l15 = tid & 15;
  const int quad = (tid >> 4) & 3;
  const int wband = tid >> 6;
  const int eloc = wband * 16 + l15;  // this lane's edge (block-local)

  // ---- phase 0a: per-lane edge read + B-frag: ad = q[dst]-k[src] (f16)
  int s_mine, d_mine;
  f16x8 bfrag[2];
  float dp0, dp1, dp2;
  {
    const int e = eb + eloc;
    int2 sd = make_int2(0, 0);
    int valid_d = -1;
    if (e < ET) {
      sd = srt[e];
      valid_d = sd.y;
    }
    s_mine = sd.x;
    d_mine = sd.y;
    if (quad == 0) dsts[eloc] = valid_d;
#pragma unroll
    for (int ks = 0; ks < 2; ++ks) {
      const f16x8 qv =
          *(const f16x8*)(qh + (size_t)d_mine * 64 + ks * 32 + quad * 8);
      const f16x8 kv =
          *(const f16x8*)(kh + (size_t)s_mine * 64 + ks * 32 + quad * 8);
      bfrag[ks] = qv - kv;
    }
    dp0 = pos[(size_t)d_mine * 3 + 0] - pos[(size_t)s_mine * 3 + 0];
    dp1 = pos[(size_t)d_mine * 3 + 1] - pos[(size_t)s_mine * 3 + 1];
    dp2 = pos[(size_t)d_mine * 3 + 2] - pos[(size_t)s_mine * 3 + 2];
  }

  // ---- phase 0b: stage weights (f16), biases, posw1T
  load_whf(W1, att_w1, tid);
  load_whf(W2, att_w2, tid);
  load_whf(PW2, pos_w2, tid);
  if (tid < 64) {
    b1s[tid] = att_b1[tid];
    b2s[tid] = att_b2[tid];
    pb1s[tid] = pos_b1[tid];
    pb2s[tid] = pos_b2[tid];
    posw1T[0 * 64 + tid] = pos_w1[tid * 3 + 0];
    posw1T[1 * 64 + tid] = pos_w1[tid * 3 + 1];
    posw1T[2 * 64 + tid] = pos_w1[tid * 3 + 2];
  }
  __syncthreads();  // B0

  // ---- GEMM1: h1 = relu(W1 . ad^T + b1) -> h1 rows [e][h] f16
#pragma unroll
  for (int t = 0; t < 4; ++t) {
    f32x4 acc = {0.f, 0.f, 0.f, 0.f};
#pragma unroll
    for (int ks = 0; ks < 2; ++ks) {
      const f16x8 af = frag_ldh(W1, t * 16 + l15, ks * 32 + quad * 8);
      acc = __builtin_amdgcn_mfma_f32_16x16x32_f16(af, bfrag[ks], acc, 0, 0, 0);
    }
    const int hb = t * 16 + quad * 4;
    *(f16x4*)(h1 + eloc * 72 + hb) =
        pk4(fmaxf(acc[0] + b1s[hb + 0], 0.f), fmaxf(acc[1] + b1s[hb + 1], 0.f),
            fmaxf(acc[2] + b1s[hb + 2], 0.f), fmaxf(acc[3] + b1s[hb + 3], 0.f));
  }

  // ---- hp in registers: hp[i] = relu(pb1[i] + sum_k dp[k]*posw1T[k][i]),
  // exactly the 16 i-values this lane's GEMM3 B-frag needs.
  f16x8 hpfrag[2];
#pragma unroll
  for (int ks = 0; ks < 2; ++ks) {
    float hv[8];
#pragma unroll
    for (int j = 0; j < 8; ++j) {
      const int i = ks * 32 + quad * 8 + j;
      float a = pb1s[i];
      a = fmaf(dp0, posw1T[i], a);
      a = fmaf(dp1, posw1T[64 + i], a);
      a = fmaf(dp2, posw1T[128 + i], a);
      hv[j] = fmaxf(a, 0.f);
    }
    const f16x4 lo = pk4(hv[0], hv[1], hv[2], hv[3]);
    const f16x4 hi = pk4(hv[4], hv[5], hv[6], hv[7]);
    hpfrag[ks] = __builtin_shufflevector(lo, hi, 0, 1, 2, 3, 4, 5, 6, 7);
  }
  __syncthreads();  // B1: h1 visible

  // ---- GEMM2: alpha = relu(W2 . h1^T + b2); ex = exp(alpha)  (regs)
  float ex[16], del[16];
  {
    f16x8 hfrag[2];
#pragma unroll
    for (int ks = 0; ks < 2; ++ks)
      hfrag[ks] = frag_ldh(h1, eloc, ks * 32 + quad * 8);
#pragma unroll
    for (int t = 0; t < 4; ++t) {
      f32x4 acc = {0.f, 0.f, 0.f, 0.f};
#pragma unroll
      for (int ks = 0; ks < 2; ++ks) {
        const f16x8 af = frag_ldh(W2, t * 16 + l15, ks * 32 + quad * 8);
        acc = __builtin_amdgcn_mfma_f32_16x16x32_f16(af, hfrag[ks], acc, 0, 0, 0);
      }
      const int ob = t * 16 + quad * 4;
#pragma unroll
      for (int r = 0; r < 4; ++r)
        ex[t * 4 + r] = __expf(fmaxf(acc[r] + b2s[ob + r], 0.f));
    }
  }
  // ---- GEMM3: delta = relu(PW2 . hp^T + pb2)  (regs)
#pragma unroll
  for (int t = 0; t < 4; ++t) {
    f32x4 acc = {0.f, 0.f, 0.f, 0.f};
#pragma unroll
    for (int ks = 0; ks < 2; ++ks) {
      const f16x8 af = frag_ldh(PW2, t * 16 + l15, ks * 32 + quad * 8);
      acc = __builtin_amdgcn_mfma_f32_16x16x32_f16(af, hpfrag[ks], acc, 0, 0, 0);
    }
    const int ob = t * 16 + quad * 4;
#pragma unroll
    for (int r = 0; r < 4; ++r)
      del[t * 4 + r] = fmaxf(acc[r] + pb2s[ob + r], 0.f);
  }
  // v gather before the barrier (global, hides latency)
  float vr[16];
#pragma unroll
  for (int t = 0; t < 4; ++t) {
    const float4 v4 =
        *(const float4*)(vv + (size_t)s_mine * 64 + t * 16 + quad * 4);
    vr[t * 4 + 0] = v4.x;
    vr[t * 4 + 1] = v4.y;
    vr[t * 4 + 2] = v4.z;
    vr[t * 4 + 3] = v4.w;
  }
  __syncthreads();  // B2: all smem MFMA reads done -> alias region free

  // ---- phase 5: (msg, ex) -> pairb, slot = (e + 2o) & 63
#pragma unroll
  for (int t = 0; t < 4; ++t) {
#pragma unroll
    for (int r = 0; r < 4; ++r) {
      const int o = t * 16 + quad * 4 + r;
      const int sl = (eloc + 2 * o) & 63;
      const float e_ = ex[t * 4 + r];
      pairb[o * 65 + sl] = make_float2(e_ * (vr[t * 4 + r] + del[t * 4 + r]), e_);
    }
  }
  __syncthreads();  // B3

  // ---- phase 6: segmented reduce over sorted-dst runs, then atomics
  {
    const int c = tid & 63;
    const int r = tid >> 6;
    float am = 0.f, ae = 0.f;
    int cur = -1;
#pragma unroll 1
    for (int t2 = 0; t2 < 16; ++t2) {
      const int el = r * 16 + t2;
      const int d = dsts[el];
      if (d != cur) {
        if (cur >= 0) {
          unsafeAtomicAdd(num + (size_t)cur * 64 + c, am);
          unsafeAtomicAdd(den + (size_t)cur * 64 + c, ae);
        }
        cur = d;
        am = 0.f;
        ae = 0.f;
      }
      if (d >= 0) {
        const float2 pe = pairb[c * 65 + ((el + 2 * c) & 63)];
        am += pe.x;
        ae += pe.y;
      }
    }
    if (cur >= 0) {
      unsafeAtomicAdd(num + (size_t)cur * 64 + c, am);
      unsafeAtomicAdd(den + (size_t)cur * 64 + c, ae);
    }
  }
}

// ---------------------------------------------------------------------------
// Kernel C: out = relu((num/(den+1e-16)) @ W_out.T + b_out)
// ---------------------------------------------------------------------------
__global__ __launch_bounds__(256, 3) void out_proj(
    const float* __restrict__ num, const float* __restrict__ den,
    const float* __restrict__ W_out, const float* __restrict__ b_out,
    float* __restrict__ out) {
  __shared__ __align__(16) float bufY[64 * 64];
  __shared__ __align__(16) float wbuf[64 * 64];
  __shared__ __align__(16) float bias[64];

  const int tid = threadIdx.x;
  const int nb = blockIdx.x * 64;
  const int m0 = (tid & 15) * 4;
  const int o0 = (tid >> 4) * 4;

  {
    const int n = tid >> 2;
    const int kc = (tid & 3) * 16;
    const int gn = nb + n;
#pragma unroll
    for (int u = 0; u < 4; ++u) {
      float4 nm = make_float4(0.f, 0.f, 0.f, 0.f);
      float4 dn = make_float4(1.f, 1.f, 1.f, 1.f);
      if (gn < NN) {
        nm = *(const float4*)(num + (size_t)gn * 64 + kc + 4 * u);
        dn = *(const float4*)(den + (size_t)gn * 64 + kc + 4 * u);
      }
      const int kbi = kc + 4 * u;
      bufY[(kbi + 0) * 64 + n] = nm.x / (dn.x + 1e-16f);
      bufY[(kbi + 1) * 64 + n] = nm.y / (dn.y + 1e-16f);
      bufY[(kbi + 2) * 64 + n] = nm.z / (dn.z + 1e-16f);
      bufY[(kbi + 3) * 64 + n] = nm.w / (dn.w + 1e-16f);
    }
  }
  load_wT(wbuf, W_out, tid);
  if (tid < 64) bias[tid] = b_out[tid];
  __syncthreads();

  float acc[4][4] = {};
  gemm64(bufY, wbuf, m0, o0, acc);
#pragma unroll
  for (int i = 0; i < 4; ++i) {
    const int gn = nb + m0 + i;
    if (gn < NN) {
      float4 r;
      r.x = fmaxf(acc[i][0] + bias[o0 + 0], 0.f);
      r.y = fmaxf(acc[i][1] + bias[o0 + 1], 0.f);
      r.z = fmaxf(acc[i][2] + bias[o0 + 2], 0.f);
      r.w = fmaxf(acc[i][3] + bias[o0 + 3], 0.f);
      *(float4*)(out + (size_t)gn * 64 + o0) = r;
    }
  }
}

extern "C" void kernel_launch(void* const* d_in, const int* in_sizes, int n_in,
                              void* d_out, int out_size, void* d_ws,
                              size_t ws_size, hipStream_t stream) {
  const float* x      = (const float*)d_in[0];
  const float* pos    = (const float*)d_in[1];
  const int*   ei     = (const int*)d_in[2];
  const float* W_in   = (const float*)d_in[3];
  const float* b_in   = (const float*)d_in[4];
  const float* W_out  = (const float*)d_in[5];
  const float* b_out  = (const float*)d_in[6];
  const float* W_lin  = (const float*)d_in[7];
  const float* W_src  = (const float*)d_in[8];
  const float* W_dst  = (const float*)d_in[9];
  const float* pos_w1 = (const float*)d_in[10];
  const float* pos_b1 = (const float*)d_in[11];
  const float* pos_w2 = (const float*)d_in[12];
  const float* pos_b2 = (const float*)d_in[13];
  const float* att_w1 = (const float*)d_in[14];
  const float* att_b1 = (const float*)d_in[15];
  const float* att_w2 = (const float*)d_in[16];
  const float* att_b2 = (const float*)d_in[17];

  float* ws = (float*)d_ws;
  const size_t NC = (size_t)NN * C;
  float* v   = ws;                       // NC f32
  float* num = ws + NC;                  // NC f32
  float* den = ws + 2 * NC;              // NC f32
  _Float16* kh = (_Float16*)(ws + 3 * NC);  // NC f16
  _Float16* qh = kh + NC;                    // NC f16
  int* ib    = (int*)(qh + NC);
  int* cnt   = ib;                       // NN
  int* curs  = ib + NN;                  // NN
  int* bsum  = ib + 2 * NN;              // NBLK
  int2* srt  = (int2*)(((uintptr_t)(bsum + NBLK) + 15) & ~(uintptr_t)15);

  hipMemsetAsync(num, 0, 2 * NC * sizeof(float), stream);
  hipMemsetAsync(cnt, 0, NN * sizeof(int), stream);

  const dim3 blk(256);
  node_proj<<<dim3((NN + 63) / 64), blk, 0, stream>>>(
      x, W_in, b_in, W_lin, W_src, W_dst, ei, cnt, v, kh, qh);
  scan_partial<<<dim3(NBLK), blk, 0, stream>>>(cnt, bsum);
  scan_final<<<dim3(NBLK), blk, 0, stream>>>(cnt, bsum, curs);
  scatter_kernel<<<dim3((ET + 255) / 256), blk, 0, stream>>>(ei, curs, srt);
  edge_pass<<<dim3((ET + 63) / 64), blk, 0, stream>>>(
      srt, pos, v, kh, qh, att_w1, att_b1, att_w2, att_b2, pos_w1, pos_b1,
      pos_w2, pos_b2, num, den);
  out_proj<<<dim3((NN + 63) / 64), blk, 0, stream>>>(num, den, W_out, b_out,
                                                     (float*)d_out);
}

// Round 7
// 315.269 us; speedup vs baseline: 5.0310x; 1.0926x over previous
//
#include <hip/hip_runtime.h>
#include <math.h>

#define NN 50000
#define EE 800000
#define ET (EE + NN)   // 850000 edges incl. self-loops
#define C  64
#define NBLK 49        // ceil(NN/1024) scan blocks

typedef __attribute__((ext_vector_type(8))) _Float16 f16x8;
typedef __attribute__((ext_vector_type(4))) _Float16 f16x4;
typedef __attribute__((ext_vector_type(2))) _Float16 f16x2;
typedef __attribute__((ext_vector_type(4))) float f32x4;

__device__ __forceinline__ f16x2 pk2(float a, float b) {
  return __builtin_bit_cast(f16x2, __builtin_amdgcn_cvt_pkrtz(a, b));
}
__device__ __forceinline__ f16x4 pk4(float a, float b, float c, float d) {
  return __builtin_shufflevector(pk2(a, b), pk2(c, d), 0, 1, 2, 3);
}
__device__ __forceinline__ f16x8 pk8(const float* y) {
  const f16x4 lo = pk4(y[0], y[1], y[2], y[3]);
  const f16x4 hi = pk4(y[4], y[5], y[6], y[7]);
  return __builtin_shufflevector(lo, hi, 0, 1, 2, 3, 4, 5, 6, 7);
}

// f16 LDS row read: 8 consecutive k at 16B alignment (stride 72 halves)
__device__ __forceinline__ f16x8 frag_ldh(const _Float16* base, int row,
                                          int kofs) {
  return *(const f16x8*)(base + row * 72 + kofs);
}

// Copy one 64x64 f16 weight from global (row-major 64) to LDS (stride 72).
__device__ __forceinline__ void stage_w(_Float16* __restrict__ dst,
                                        const _Float16* __restrict__ src16,
                                        int tid) {
  const f16x8* src = (const f16x8*)(src16 + tid * 16);
  _Float16* d = dst + (tid >> 2) * 72 + (tid & 3) * 16;
  ((f16x8*)d)[0] = src[0];
  ((f16x8*)d)[1] = src[1];
}

// ---------------------------------------------------------------------------
// prep: convert 8 weight matrices f32 -> f16 (one block each)
// order: W_in, W_lin, W_src, W_dst, att_w1, att_w2, pos_w2, W_out
// ---------------------------------------------------------------------------
__global__ __launch_bounds__(256) void prep_kernel(
    const float* __restrict__ W_in, const float* __restrict__ W_lin,
    const float* __restrict__ W_src, const float* __restrict__ W_dst,
    const float* __restrict__ att_w1, const float* __restrict__ att_w2,
    const float* __restrict__ pos_w2, const float* __restrict__ W_out,
    _Float16* __restrict__ w16) {
  const float* Ws[8] = {W_in, W_lin, W_src, W_dst, att_w1, att_w2, pos_w2, W_out};
  const float* src = Ws[blockIdx.x];
  _Float16* dst = w16 + blockIdx.x * 4096;
#pragma unroll
  for (int i = threadIdx.x * 4; i < 4096; i += 1024) {
    const float4 w = *(const float4*)(src + i);
    *(f16x4*)(dst + i) = pk4(w.x, w.y, w.z, w.w);
  }
}

// ---------------------------------------------------------------------------
// Scan: per-block partial sums, then final (block offsets re-derived in-block)
// ---------------------------------------------------------------------------
__global__ __launch_bounds__(256) void scan_partial(const int* __restrict__ cnt,
                                                    int* __restrict__ bsum) {
  __shared__ int ws[4];
  const int t = threadIdx.x;
  const int base = blockIdx.x * 1024 + t * 4;
  int s = 0;
  if (base + 3 < NN) {
    const int4 v = *(const int4*)(cnt + base);
    s = v.x + v.y + v.z + v.w;
  } else {
#pragma unroll
    for (int i = 0; i < 4; ++i)
      if (base + i < NN) s += cnt[base + i];
  }
#pragma unroll
  for (int off = 32; off; off >>= 1) s += __shfl_down(s, off, 64);
  if ((t & 63) == 0) ws[t >> 6] = s;
  __syncthreads();
  if (t == 0) bsum[blockIdx.x] = ws[0] + ws[1] + ws[2] + ws[3];
}

__global__ __launch_bounds__(256) void scan_final(const int* __restrict__ cnt,
                                                  const int* __restrict__ bsum,
                                                  int* __restrict__ curs) {
  __shared__ int tsum[256];
  __shared__ int sblk[64];
  const int t = threadIdx.x;
  if (t < 64) {
    const int mine = (t < NBLK) ? bsum[t] : 0;
    int v = mine;
#pragma unroll
    for (int off = 1; off < 64; off <<= 1) {
      const int u = __shfl_up(v, off, 64);
      if (t >= off) v += u;
    }
    sblk[t] = v - mine;
  }
  const int base = blockIdx.x * 1024 + t * 4;
  int v[4] = {0, 0, 0, 0};
  if (base + 3 < NN) {
    const int4 x = *(const int4*)(cnt + base);
    v[0] = x.x; v[1] = x.y; v[2] = x.z; v[3] = x.w;
  } else {
#pragma unroll
    for (int i = 0; i < 4; ++i)
      if (base + i < NN) v[i] = cnt[base + i];
  }
  const int s = v[0] + v[1] + v[2] + v[3];
  tsum[t] = s;
  __syncthreads();
  for (int off = 1; off < 256; off <<= 1) {
    const int u = (t >= off) ? tsum[t - off] : 0;
    __syncthreads();
    tsum[t] += u;
    __syncthreads();
  }
  int ex = sblk[blockIdx.x] + tsum[t] - s;
#pragma unroll
  for (int i = 0; i < 4; ++i) {
    if (base + i < NN) curs[base + i] = ex;
    ex += v[i];
  }
}

__global__ void scatter_kernel(const int* __restrict__ ei,
                               int* __restrict__ curs, int2* __restrict__ srt) {
  const int e0 = (blockIdx.x * 256 + threadIdx.x) * 4;
  if (e0 >= ET) return;
  int s[4], d[4];
  if (e0 + 3 < EE) {
    const int4 sv = *(const int4*)(ei + e0);
    const int4 dv = *(const int4*)(ei + EE + e0);
    s[0] = sv.x; s[1] = sv.y; s[2] = sv.z; s[3] = sv.w;
    d[0] = dv.x; d[1] = dv.y; d[2] = dv.z; d[3] = dv.w;
  } else {
#pragma unroll
    for (int i = 0; i < 4; ++i) {
      const int e = e0 + i;
      if (e < EE) {
        s[i] = ei[e];
        d[i] = ei[EE + e];
      } else if (e < ET) {
        s[i] = d[i] = e - EE;
      } else {
        s[i] = d[i] = -1;
      }
    }
  }
#pragma unroll
  for (int i = 0; i < 4; ++i) {
    if (d[i] >= 0) {
      const int p = atomicAdd(&curs[d[i]], 1);
      srt[p] = make_int2(s[i], d[i]);
    }
  }
}

// ---------------------------------------------------------------------------
// Kernel A: fused histogram + node projections, all MFMA f16.
// h = relu(x@W_in.T+b); v/k/q = h@W.T -> f16 outputs. 2 barriers.
// ---------------------------------------------------------------------------
__global__ __launch_bounds__(256, 3) void node_proj(
    const float* __restrict__ x, const float* __restrict__ b_in,
    const _Float16* __restrict__ w16, const int* __restrict__ ei,
    int* __restrict__ cnt, _Float16* __restrict__ vh,
    _Float16* __restrict__ kh, _Float16* __restrict__ qh) {
  __shared__ __align__(16) _Float16 wlds[4 * 4608];  // W_in|W_lin|W_src|W_dst
  __shared__ __align__(16) _Float16 hlds[4608];
  __shared__ float biasv[64];

  const int tid = threadIdx.x;
  const int nb = blockIdx.x * 64;
  const int l15 = tid & 15;
  const int quad = (tid >> 4) & 3;
  const int wband = tid >> 6;
  const int nloc = wband * 16 + l15;
  const int gn = nb + nloc;

  // fire-and-forget histogram
  {
    const int stride = gridDim.x * 256;
    for (int e = blockIdx.x * 256 + tid; e < ET; e += stride) {
      const int d = (e < EE) ? ei[EE + e] : (e - EE);
      atomicAdd(&cnt[d], 1);
    }
  }

#pragma unroll
  for (int w = 0; w < 4; ++w) stage_w(wlds + w * 4608, w16 + w * 4096, tid);
  if (tid < 64) biasv[tid] = b_in[tid];

  // B-frag from x (f32 -> f16)
  f16x8 bfrag[2];
#pragma unroll
  for (int ks = 0; ks < 2; ++ks) {
    float y[8] = {0.f, 0.f, 0.f, 0.f, 0.f, 0.f, 0.f, 0.f};
    if (gn < NN) {
      const float4 a = *(const float4*)(x + (size_t)gn * 64 + ks * 32 + quad * 8);
      const float4 b = *(const float4*)(x + (size_t)gn * 64 + ks * 32 + quad * 8 + 4);
      y[0] = a.x; y[1] = a.y; y[2] = a.z; y[3] = a.w;
      y[4] = b.x; y[5] = b.y; y[6] = b.z; y[7] = b.w;
    }
    bfrag[ks] = pk8(y);
  }
  __syncthreads();  // B0

  // GEMM1: h = relu(W_in . x^T + b) -> hlds rows [n][o] f16
#pragma unroll
  for (int t = 0; t < 4; ++t) {
    f32x4 acc = {0.f, 0.f, 0.f, 0.f};
#pragma unroll
    for (int ks = 0; ks < 2; ++ks) {
      const f16x8 af = frag_ldh(wlds, t * 16 + l15, ks * 32 + quad * 8);
      acc = __builtin_amdgcn_mfma_f32_16x16x32_f16(af, bfrag[ks], acc, 0, 0, 0);
    }
    const int hb = t * 16 + quad * 4;
    *(f16x4*)(hlds + nloc * 72 + hb) =
        pk4(fmaxf(acc[0] + biasv[hb + 0], 0.f), fmaxf(acc[1] + biasv[hb + 1], 0.f),
            fmaxf(acc[2] + biasv[hb + 2], 0.f), fmaxf(acc[3] + biasv[hb + 3], 0.f));
  }
  __syncthreads();  // B1

  f16x8 hfrag[2];
#pragma unroll
  for (int ks = 0; ks < 2; ++ks)
    hfrag[ks] = frag_ldh(hlds, nloc, ks * 32 + quad * 8);

  _Float16* outs[3] = {vh, kh, qh};
#pragma unroll
  for (int p = 0; p < 3; ++p) {
    const _Float16* W = wlds + (p + 1) * 4608;
#pragma unroll
    for (int t = 0; t < 4; ++t) {
      f32x4 acc = {0.f, 0.f, 0.f, 0.f};
#pragma unroll
      for (int ks = 0; ks < 2; ++ks) {
        const f16x8 af = frag_ldh(W, t * 16 + l15, ks * 32 + quad * 8);
        acc = __builtin_amdgcn_mfma_f32_16x16x32_f16(af, hfrag[ks], acc, 0, 0, 0);
      }
      if (gn < NN) {
        *(f16x4*)(outs[p] + (size_t)gn * 64 + t * 16 + quad * 4) =
            pk4(acc[0], acc[1], acc[2], acc[3]);
      }
    }
  }
}

// ---------------------------------------------------------------------------
// Kernel B: MFMA (f16) edge pass, 4 barriers. Wave w owns edges [w*16,w*16+16).
// ---------------------------------------------------------------------------
__global__ __launch_bounds__(256, 4) void edge_pass(
    const int2* __restrict__ srt, const float* __restrict__ pos,
    const _Float16* __restrict__ vh, const _Float16* __restrict__ kh,
    const _Float16* __restrict__ qh, const _Float16* __restrict__ w16,
    const float* __restrict__ att_b1, const float* __restrict__ att_b2,
    const float* __restrict__ pos_w1, const float* __restrict__ pos_b1,
    const float* __restrict__ pos_b2, float* __restrict__ num,
    float* __restrict__ den) {
  // 36864B: W1 | W2 | PW2 | h1, each 64 rows x stride 72 f16.
  // After B2 reused as pairb (float2[64*65] = 33280B).
  __shared__ __align__(16) _Float16 smem[18432];
  __shared__ __align__(16) float posw1T[3 * 64];
  __shared__ float b1s[64], b2s[64], pb1s[64], pb2s[64];
  __shared__ int dsts[64];

  _Float16* W1  = smem;
  _Float16* W2  = smem + 4608;
  _Float16* PW2 = smem + 9216;
  _Float16* h1  = smem + 13824;
  float2* pairb = (float2*)smem;  // (msg, ex) interleaved

  const int tid = threadIdx.x;
  const int eb = blockIdx.x * 64;
  const int l15 = tid & 15;
  const int quad = (tid >> 4) & 3;
  const int wband = tid >> 6;
  const int eloc = wband * 16 + l15;

  // ---- phase 0a: per-lane edge read + B-frag: ad = q[dst]-k[src] (f16)
  int s_mine, d_mine;
  f16x8 bfrag[2];
  float dp0, dp1, dp2;
  {
    const int e = eb + eloc;
    int2 sd = make_int2(0, 0);
    int valid_d = -1;
    if (e < ET) {
      sd = srt[e];
      valid_d = sd.y;
    }
    s_mine = sd.x;
    d_mine = sd.y;
    if (quad == 0) dsts[eloc] = valid_d;
#pragma unroll
    for (int ks = 0; ks < 2; ++ks) {
      const f16x8 qv =
          *(const f16x8*)(qh + (size_t)d_mine * 64 + ks * 32 + quad * 8);
      const f16x8 kv =
          *(const f16x8*)(kh + (size_t)s_mine * 64 + ks * 32 + quad * 8);
      bfrag[ks] = qv - kv;
    }
    dp0 = pos[(size_t)d_mine * 3 + 0] - pos[(size_t)s_mine * 3 + 0];
    dp1 = pos[(size_t)d_mine * 3 + 1] - pos[(size_t)s_mine * 3 + 1];
    dp2 = pos[(size_t)d_mine * 3 + 2] - pos[(size_t)s_mine * 3 + 2];
  }

  // ---- phase 0b: stage pre-converted f16 weights (att_w1=4, att_w2=5, pos_w2=6)
  stage_w(W1, w16 + 4 * 4096, tid);
  stage_w(W2, w16 + 5 * 4096, tid);
  stage_w(PW2, w16 + 6 * 4096, tid);
  if (tid < 64) {
    b1s[tid] = att_b1[tid];
    b2s[tid] = att_b2[tid];
    pb1s[tid] = pos_b1[tid];
    pb2s[tid] = pos_b2[tid];
    posw1T[0 * 64 + tid] = pos_w1[tid * 3 + 0];
    posw1T[1 * 64 + tid] = pos_w1[tid * 3 + 1];
    posw1T[2 * 64 + tid] = pos_w1[tid * 3 + 2];
  }
  __syncthreads();  // B0

  // ---- GEMM1: h1 = relu(W1 . ad^T + b1) -> h1 rows [e][h] f16
#pragma unroll
  for (int t = 0; t < 4; ++t) {
    f32x4 acc = {0.f, 0.f, 0.f, 0.f};
#pragma unroll
    for (int ks = 0; ks < 2; ++ks) {
      const f16x8 af = frag_ldh(W1, t * 16 + l15, ks * 32 + quad * 8);
      acc = __builtin_amdgcn_mfma_f32_16x16x32_f16(af, bfrag[ks], acc, 0, 0, 0);
    }
    const int hb = t * 16 + quad * 4;
    *(f16x4*)(h1 + eloc * 72 + hb) =
        pk4(fmaxf(acc[0] + b1s[hb + 0], 0.f), fmaxf(acc[1] + b1s[hb + 1], 0.f),
            fmaxf(acc[2] + b1s[hb + 2], 0.f), fmaxf(acc[3] + b1s[hb + 3], 0.f));
  }

  // ---- hp in registers (k=3 pos-MLP layer 1 for this lane's 16 k-values)
  f16x8 hpfrag[2];
#pragma unroll
  for (int ks = 0; ks < 2; ++ks) {
    float hv[8];
#pragma unroll
    for (int j = 0; j < 8; ++j) {
      const int i = ks * 32 + quad * 8 + j;
      float a = pb1s[i];
      a = fmaf(dp0, posw1T[i], a);
      a = fmaf(dp1, posw1T[64 + i], a);
      a = fmaf(dp2, posw1T[128 + i], a);
      hv[j] = fmaxf(a, 0.f);
    }
    hpfrag[ks] = pk8(hv);
  }
  __syncthreads();  // B1: h1 visible

  // ---- GEMM2: alpha = relu(W2 . h1^T + b2); ex = exp(alpha)
  float ex[16], del[16];
  {
    f16x8 hfrag[2];
#pragma unroll
    for (int ks = 0; ks < 2; ++ks)
      hfrag[ks] = frag_ldh(h1, eloc, ks * 32 + quad * 8);
#pragma unroll
    for (int t = 0; t < 4; ++t) {
      f32x4 acc = {0.f, 0.f, 0.f, 0.f};
#pragma unroll
      for (int ks = 0; ks < 2; ++ks) {
        const f16x8 af = frag_ldh(W2, t * 16 + l15, ks * 32 + quad * 8);
        acc = __builtin_amdgcn_mfma_f32_16x16x32_f16(af, hfrag[ks], acc, 0, 0, 0);
      }
      const int ob = t * 16 + quad * 4;
#pragma unroll
      for (int r = 0; r < 4; ++r)
        ex[t * 4 + r] = __expf(fmaxf(acc[r] + b2s[ob + r], 0.f));
    }
  }
  // ---- GEMM3: delta = relu(PW2 . hp^T + pb2)
#pragma unroll
  for (int t = 0; t < 4; ++t) {
    f32x4 acc = {0.f, 0.f, 0.f, 0.f};
#pragma unroll
    for (int ks = 0; ks < 2; ++ks) {
      const f16x8 af = frag_ldh(PW2, t * 16 + l15, ks * 32 + quad * 8);
      acc = __builtin_amdgcn_mfma_f32_16x16x32_f16(af, hpfrag[ks], acc, 0, 0, 0);
    }
    const int ob = t * 16 + quad * 4;
#pragma unroll
    for (int r = 0; r < 4; ++r)
      del[t * 4 + r] = fmaxf(acc[r] + pb2s[ob + r], 0.f);
  }
  // v gather (f16, 8B per chunk)
  float vr[16];
#pragma unroll
  for (int t = 0; t < 4; ++t) {
    const f16x4 v4 = *(const f16x4*)(vh + (size_t)s_mine * 64 + t * 16 + quad * 4);
    vr[t * 4 + 0] = (float)v4[0];
    vr[t * 4 + 1] = (float)v4[1];
    vr[t * 4 + 2] = (float)v4[2];
    vr[t * 4 + 3] = (float)v4[3];
  }
  __syncthreads();  // B2: all smem MFMA reads done -> alias region free

  // ---- phase 5: (msg, ex) -> pairb, slot = (e + 2o) & 63
#pragma unroll
  for (int t = 0; t < 4; ++t) {
#pragma unroll
    for (int r = 0; r < 4; ++r) {
      const int o = t * 16 + quad * 4 + r;
      const int sl = (eloc + 2 * o) & 63;
      const float e_ = ex[t * 4 + r];
      pairb[o * 65 + sl] = make_float2(e_ * (vr[t * 4 + r] + del[t * 4 + r]), e_);
    }
  }
  __syncthreads();  // B3

  // ---- phase 6: segmented reduce over sorted-dst runs, then atomics
  {
    const int c = tid & 63;
    const int r = tid >> 6;
    float am = 0.f, ae = 0.f;
    int cur = -1;
#pragma unroll 1
    for (int t2 = 0; t2 < 16; ++t2) {
      const int el = r * 16 + t2;
      const int d = dsts[el];
      if (d != cur) {
        if (cur >= 0) {
          unsafeAtomicAdd(num + (size_t)cur * 64 + c, am);
          unsafeAtomicAdd(den + (size_t)cur * 64 + c, ae);
        }
        cur = d;
        am = 0.f;
        ae = 0.f;
      }
      if (d >= 0) {
        const float2 pe = pairb[c * 65 + ((el + 2 * c) & 63)];
        am += pe.x;
        ae += pe.y;
      }
    }
    if (cur >= 0) {
      unsafeAtomicAdd(num + (size_t)cur * 64 + c, am);
      unsafeAtomicAdd(den + (size_t)cur * 64 + c, ae);
    }
  }
}

// ---------------------------------------------------------------------------
// Kernel C: out = relu((num/(den+1e-16)) @ W_out.T + b_out), MFMA f16.
// ---------------------------------------------------------------------------
__global__ __launch_bounds__(256, 4) void out_proj(
    const float* __restrict__ num, const float* __restrict__ den,
    const _Float16* __restrict__ w16, const float* __restrict__ b_out,
    float* __restrict__ out) {
  __shared__ __align__(16) _Float16 wlds[4608];
  __shared__ float biasv[64];

  const int tid = threadIdx.x;
  const int nb = blockIdx.x * 64;
  const int l15 = tid & 15;
  const int quad = (tid >> 4) & 3;
  const int wband = tid >> 6;
  const int gn = nb + wband * 16 + l15;

  stage_w(wlds, w16 + 7 * 4096, tid);
  if (tid < 64) biasv[tid] = b_out[tid];

  f16x8 bfrag[2];
#pragma unroll
  for (int ks = 0; ks < 2; ++ks) {
    float y[8] = {0.f, 0.f, 0.f, 0.f, 0.f, 0.f, 0.f, 0.f};
    if (gn < NN) {
      const size_t base = (size_t)gn * 64 + ks * 32 + quad * 8;
      const float4 n0 = *(const float4*)(num + base);
      const float4 n1 = *(const float4*)(num + base + 4);
      const float4 d0 = *(const float4*)(den + base);
      const float4 d1 = *(const float4*)(den + base + 4);
      y[0] = n0.x / (d0.x + 1e-16f); y[1] = n0.y / (d0.y + 1e-16f);
      y[2] = n0.z / (d0.z + 1e-16f); y[3] = n0.w / (d0.w + 1e-16f);
      y[4] = n1.x / (d1.x + 1e-16f); y[5] = n1.y / (d1.y + 1e-16f);
      y[6] = n1.z / (d1.z + 1e-16f); y[7] = n1.w / (d1.w + 1e-16f);
    }
    bfrag[ks] = pk8(y);
  }
  __syncthreads();

#pragma unroll
  for (int t = 0; t < 4; ++t) {
    f32x4 acc = {0.f, 0.f, 0.f, 0.f};
#pragma unroll
    for (int ks = 0; ks < 2; ++ks) {
      const f16x8 af = frag_ldh(wlds, t * 16 + l15, ks * 32 + quad * 8);
      acc = __builtin_amdgcn_mfma_f32_16x16x32_f16(af, bfrag[ks], acc, 0, 0, 0);
    }
    if (gn < NN) {
      const int ob = t * 16 + quad * 4;
      float4 r;
      r.x = fmaxf(acc[0] + biasv[ob + 0], 0.f);
      r.y = fmaxf(acc[1] + biasv[ob + 1], 0.f);
      r.z = fmaxf(acc[2] + biasv[ob + 2], 0.f);
      r.w = fmaxf(acc[3] + biasv[ob + 3], 0.f);
      *(float4*)(out + (size_t)gn * 64 + ob) = r;
    }
  }
}

extern "C" void kernel_launch(void* const* d_in, const int* in_sizes, int n_in,
                              void* d_out, int out_size, void* d_ws,
                              size_t ws_size, hipStream_t stream) {
  const float* x      = (const float*)d_in[0];
  const float* pos    = (const float*)d_in[1];
  const int*   ei     = (const int*)d_in[2];
  const float* W_in   = (const float*)d_in[3];
  const float* b_in   = (const float*)d_in[4];
  const float* W_out  = (const float*)d_in[5];
  const float* b_out  = (const float*)d_in[6];
  const float* W_lin  = (const float*)d_in[7];
  const float* W_src  = (const float*)d_in[8];
  const float* W_dst  = (const float*)d_in[9];
  const float* pos_w1 = (const float*)d_in[10];
  const float* pos_b1 = (const float*)d_in[11];
  const float* pos_w2 = (const float*)d_in[12];
  const float* pos_b2 = (const float*)d_in[13];
  const float* att_w1 = (const float*)d_in[14];
  const float* att_b1 = (const float*)d_in[15];
  const float* att_w2 = (const float*)d_in[16];
  const float* att_b2 = (const float*)d_in[17];

  float* ws = (float*)d_ws;
  const size_t NC = (size_t)NN * C;
  float* num = ws;                       // NC f32
  float* den = ws + NC;                  // NC f32
  _Float16* vh = (_Float16*)(ws + 2 * NC);  // NC f16
  _Float16* kh = vh + NC;                    // NC f16
  _Float16* qh = kh + NC;                    // NC f16
  _Float16* w16 = qh + NC;                   // 8*4096 f16
  int* ib    = (int*)(w16 + 8 * 4096);
  int* cnt   = ib;                       // NN
  int* curs  = ib + NN;                  // NN
  int* bsum  = ib + 2 * NN;              // NBLK
  int2* srt  = (int2*)(((uintptr_t)(bsum + NBLK) + 15) & ~(uintptr_t)15);

  hipMemsetAsync(num, 0, 2 * NC * sizeof(float), stream);
  hipMemsetAsync(cnt, 0, NN * sizeof(int), stream);

  const dim3 blk(256);
  prep_kernel<<<dim3(8), blk, 0, stream>>>(W_in, W_lin, W_src, W_dst, att_w1,
                                           att_w2, pos_w2, W_out, w16);
  node_proj<<<dim3((NN + 63) / 64), blk, 0, stream>>>(x, b_in, w16, ei, cnt, vh,
                                                      kh, qh);
  scan_partial<<<dim3(NBLK), blk, 0, stream>>>(cnt, bsum);
  scan_final<<<dim3(NBLK), blk, 0, stream>>>(cnt, bsum, curs);
  scatter_kernel<<<dim3((ET + 1023) / 1024), blk, 0, stream>>>(ei, curs, srt);
  edge_pass<<<dim3((ET + 63) / 64), blk, 0, stream>>>(
      srt, pos, vh, kh, qh, w16, att_b1, att_b2, pos_w1, pos_b1, pos_b2, num,
      den);
  out_proj<<<dim3((NN + 63) / 64), blk, 0, stream>>>(num, den, w16, b_out,
                                                     (float*)d_out);
}

// Round 8
// 307.252 us; speedup vs baseline: 5.1623x; 1.0261x over previous
//
#include <hip/hip_runtime.h>
#include <math.h>

#define NN 50000
#define EE 800000
#define ET (EE + NN)   // 850000 edges incl. self-loops
#define C  64
#define NBLK 49        // ceil(NN/1024) scan blocks
#define NCHUNK 831     // ceil(ET/1024) edge chunks
#define ZBLK 463       // zeroing blocks appended to scan_partial

typedef __attribute__((ext_vector_type(8))) _Float16 f16x8;
typedef __attribute__((ext_vector_type(4))) _Float16 f16x4;
typedef __attribute__((ext_vector_type(2))) _Float16 f16x2;
typedef __attribute__((ext_vector_type(4))) float f32x4;

__device__ __forceinline__ f16x2 pk2(float a, float b) {
  return __builtin_bit_cast(f16x2, __builtin_amdgcn_cvt_pkrtz(a, b));
}
__device__ __forceinline__ f16x4 pk4(float a, float b, float c, float d) {
  return __builtin_shufflevector(pk2(a, b), pk2(c, d), 0, 1, 2, 3);
}
__device__ __forceinline__ f16x8 pk8(const float* y) {
  const f16x4 lo = pk4(y[0], y[1], y[2], y[3]);
  const f16x4 hi = pk4(y[4], y[5], y[6], y[7]);
  return __builtin_shufflevector(lo, hi, 0, 1, 2, 3, 4, 5, 6, 7);
}

// f16 LDS row read: 8 consecutive k at 16B alignment (stride 72 halves)
__device__ __forceinline__ f16x8 frag_ldh(const _Float16* base, int row,
                                          int kofs) {
  return *(const f16x8*)(base + row * 72 + kofs);
}

// Copy one 64x64 f16 weight from global (row-major 64) to LDS (stride 72).
__device__ __forceinline__ void stage_w(_Float16* __restrict__ dst,
                                        const _Float16* __restrict__ src16,
                                        int tid) {
  const f16x8* src = (const f16x8*)(src16 + tid * 16);
  _Float16* d = dst + (tid >> 2) * 72 + (tid & 3) * 16;
  ((f16x8*)d)[0] = src[0];
  ((f16x8*)d)[1] = src[1];
}

// ---------------------------------------------------------------------------
// prep: convert 8 weight matrices f32 -> f16 (one block each) + zero cnt shards
// order: W_in, W_lin, W_src, W_dst, att_w1, att_w2, pos_w2, W_out
// ---------------------------------------------------------------------------
__global__ __launch_bounds__(256) void prep_kernel(
    const float* __restrict__ W_in, const float* __restrict__ W_lin,
    const float* __restrict__ W_src, const float* __restrict__ W_dst,
    const float* __restrict__ att_w1, const float* __restrict__ att_w2,
    const float* __restrict__ pos_w2, const float* __restrict__ W_out,
    _Float16* __restrict__ w16, int* __restrict__ cnt2) {
  const float* Ws[8] = {W_in, W_lin, W_src, W_dst, att_w1, att_w2, pos_w2, W_out};
  const float* src = Ws[blockIdx.x];
  _Float16* dst = w16 + blockIdx.x * 4096;
#pragma unroll
  for (int i = threadIdx.x * 4; i < 4096; i += 1024) {
    const float4 w = *(const float4*)(src + i);
    *(f16x4*)(dst + i) = pk4(w.x, w.y, w.z, w.w);
  }
  // zero this block's counter shard (NN ints)
  int4* cz = (int4*)(cnt2 + blockIdx.x * NN);
#pragma unroll 1
  for (int i = threadIdx.x; i < NN / 4; i += 256) cz[i] = make_int4(0, 0, 0, 0);
}

// ---------------------------------------------------------------------------
// Scan over sharded counters; extra blocks zero num/den.
// ---------------------------------------------------------------------------
__global__ __launch_bounds__(256) void scan_partial(const int* __restrict__ cnt2,
                                                    int* __restrict__ bsum,
                                                    float* __restrict__ zeroreg) {
  const int t = threadIdx.x;
  if (blockIdx.x >= NBLK) {
    // zero num/den: 2*NN*64 floats
    const int zb = blockIdx.x - NBLK;
    float4* dst = (float4*)zeroreg;
    const int total4 = 2 * NN * 64 / 4;
    const float4 z = make_float4(0.f, 0.f, 0.f, 0.f);
#pragma unroll 1
    for (int i = zb * 256 + t; i < total4; i += ZBLK * 256) dst[i] = z;
    return;
  }
  __shared__ int ws[4];
  const int base = blockIdx.x * 1024 + t * 4;
  int s = 0;
  if (base + 3 < NN) {
#pragma unroll
    for (int sh = 0; sh < 8; ++sh) {
      const int4 v = *(const int4*)(cnt2 + sh * NN + base);
      s += v.x + v.y + v.z + v.w;
    }
  } else {
#pragma unroll
    for (int i = 0; i < 4; ++i)
      if (base + i < NN)
#pragma unroll
        for (int sh = 0; sh < 8; ++sh) s += cnt2[sh * NN + base + i];
  }
#pragma unroll
  for (int off = 32; off; off >>= 1) s += __shfl_down(s, off, 64);
  if ((t & 63) == 0) ws[t >> 6] = s;
  __syncthreads();
  if (t == 0) bsum[blockIdx.x] = ws[0] + ws[1] + ws[2] + ws[3];
}

__global__ __launch_bounds__(256) void scan_final(const int* __restrict__ cnt2,
                                                  const int* __restrict__ bsum,
                                                  int* __restrict__ curs2) {
  __shared__ int tsum[256];
  __shared__ int sblk[64];
  const int t = threadIdx.x;
  if (t < 64) {
    const int mine = (t < NBLK) ? bsum[t] : 0;
    int v = mine;
#pragma unroll
    for (int off = 1; off < 64; off <<= 1) {
      const int u = __shfl_up(v, off, 64);
      if (t >= off) v += u;
    }
    sblk[t] = v - mine;
  }
  const int base = blockIdx.x * 1024 + t * 4;
  int c2[8][4];
  int v[4] = {0, 0, 0, 0};
  if (base + 3 < NN) {
#pragma unroll
    for (int sh = 0; sh < 8; ++sh) {
      const int4 x = *(const int4*)(cnt2 + sh * NN + base);
      c2[sh][0] = x.x; c2[sh][1] = x.y; c2[sh][2] = x.z; c2[sh][3] = x.w;
      v[0] += x.x; v[1] += x.y; v[2] += x.z; v[3] += x.w;
    }
  } else {
#pragma unroll
    for (int sh = 0; sh < 8; ++sh)
#pragma unroll
      for (int i = 0; i < 4; ++i) {
        const int c = (base + i < NN) ? cnt2[sh * NN + base + i] : 0;
        c2[sh][i] = c;
        v[i] += c;
      }
  }
  const int s = v[0] + v[1] + v[2] + v[3];
  tsum[t] = s;
  __syncthreads();
  for (int off = 1; off < 256; off <<= 1) {
    const int u = (t >= off) ? tsum[t - off] : 0;
    __syncthreads();
    tsum[t] += u;
    __syncthreads();
  }
  int ex = sblk[blockIdx.x] + tsum[t] - s;
  // per-(shard, node) cursor bases
  int offs[8][4];
#pragma unroll
  for (int i = 0; i < 4; ++i) {
    int run = ex;
#pragma unroll
    for (int sh = 0; sh < 8; ++sh) {
      offs[sh][i] = run;
      run += c2[sh][i];
    }
    ex += v[i];
  }
  if (base + 3 < NN) {
#pragma unroll
    for (int sh = 0; sh < 8; ++sh)
      *(int4*)(curs2 + sh * NN + base) =
          make_int4(offs[sh][0], offs[sh][1], offs[sh][2], offs[sh][3]);
  } else {
#pragma unroll
    for (int sh = 0; sh < 8; ++sh)
#pragma unroll
      for (int i = 0; i < 4; ++i)
        if (base + i < NN) curs2[sh * NN + base + i] = offs[sh][i];
  }
}

// scatter: block b owns edge chunk b (1024 edges); shard = b&7 (XCD-aligned).
__global__ void scatter_kernel(const int* __restrict__ ei,
                               int* __restrict__ curs2, int2* __restrict__ srt) {
  const int chunk = blockIdx.x;
  int* cs = curs2 + (chunk & 7) * NN;
  const int e0 = chunk * 1024 + threadIdx.x * 4;
  if (e0 >= ET) return;
  int s[4], d[4];
  if (e0 + 3 < EE) {
    const int4 sv = *(const int4*)(ei + e0);
    const int4 dv = *(const int4*)(ei + EE + e0);
    s[0] = sv.x; s[1] = sv.y; s[2] = sv.z; s[3] = sv.w;
    d[0] = dv.x; d[1] = dv.y; d[2] = dv.z; d[3] = dv.w;
  } else {
#pragma unroll
    for (int i = 0; i < 4; ++i) {
      const int e = e0 + i;
      if (e < EE) {
        s[i] = ei[e];
        d[i] = ei[EE + e];
      } else if (e < ET) {
        s[i] = d[i] = e - EE;
      } else {
        s[i] = d[i] = -1;
      }
    }
  }
#pragma unroll
  for (int i = 0; i < 4; ++i) {
    if (d[i] >= 0) {
      const int p = atomicAdd(&cs[d[i]], 1);
      srt[p] = make_int2(s[i], d[i]);
    }
  }
}

// ---------------------------------------------------------------------------
// Kernel A: fused sharded histogram + node projections (MFMA f16).
// ---------------------------------------------------------------------------
__global__ __launch_bounds__(256, 3) void node_proj(
    const float* __restrict__ x, const float* __restrict__ b_in,
    const _Float16* __restrict__ w16, const int* __restrict__ ei,
    int* __restrict__ cnt2, _Float16* __restrict__ vh,
    _Float16* __restrict__ kh, _Float16* __restrict__ qh) {
  __shared__ __align__(16) _Float16 wlds[4 * 4608];  // W_in|W_lin|W_src|W_dst
  __shared__ __align__(16) _Float16 hlds[4608];
  __shared__ float biasv[64];

  const int tid = threadIdx.x;
  const int nb = blockIdx.x * 64;
  const int l15 = tid & 15;
  const int quad = (tid >> 4) & 3;
  const int wband = tid >> 6;
  const int nloc = wband * 16 + l15;
  const int gn = nb + nloc;

  // sharded fire-and-forget histogram; chunk c = edges [c*1024,(c+1)*1024)
#pragma unroll 1
  for (int chunk = blockIdx.x; chunk < NCHUNK; chunk += gridDim.x) {
    int* cs = cnt2 + (chunk & 7) * NN;
    const int e0 = chunk * 1024 + tid * 4;
    if (e0 < ET) {
      int d[4];
      if (e0 + 3 < EE) {
        const int4 dv = *(const int4*)(ei + EE + e0);
        d[0] = dv.x; d[1] = dv.y; d[2] = dv.z; d[3] = dv.w;
      } else {
#pragma unroll
        for (int i = 0; i < 4; ++i) {
          const int e = e0 + i;
          d[i] = (e < EE) ? ei[EE + e] : ((e < ET) ? e - EE : -1);
        }
      }
#pragma unroll
      for (int i = 0; i < 4; ++i)
        if (d[i] >= 0) atomicAdd(&cs[d[i]], 1);
    }
  }

#pragma unroll
  for (int w = 0; w < 4; ++w) stage_w(wlds + w * 4608, w16 + w * 4096, tid);
  if (tid < 64) biasv[tid] = b_in[tid];

  // B-frag from x (f32 -> f16)
  f16x8 bfrag[2];
#pragma unroll
  for (int ks = 0; ks < 2; ++ks) {
    float y[8] = {0.f, 0.f, 0.f, 0.f, 0.f, 0.f, 0.f, 0.f};
    if (gn < NN) {
      const float4 a = *(const float4*)(x + (size_t)gn * 64 + ks * 32 + quad * 8);
      const float4 b = *(const float4*)(x + (size_t)gn * 64 + ks * 32 + quad * 8 + 4);
      y[0] = a.x; y[1] = a.y; y[2] = a.z; y[3] = a.w;
      y[4] = b.x; y[5] = b.y; y[6] = b.z; y[7] = b.w;
    }
    bfrag[ks] = pk8(y);
  }
  __syncthreads();  // B0

  // GEMM1: h = relu(W_in . x^T + b) -> hlds rows [n][o] f16
#pragma unroll
  for (int t = 0; t < 4; ++t) {
    f32x4 acc = {0.f, 0.f, 0.f, 0.f};
#pragma unroll
    for (int ks = 0; ks < 2; ++ks) {
      const f16x8 af = frag_ldh(wlds, t * 16 + l15, ks * 32 + quad * 8);
      acc = __builtin_amdgcn_mfma_f32_16x16x32_f16(af, bfrag[ks], acc, 0, 0, 0);
    }
    const int hb = t * 16 + quad * 4;
    *(f16x4*)(hlds + nloc * 72 + hb) =
        pk4(fmaxf(acc[0] + biasv[hb + 0], 0.f), fmaxf(acc[1] + biasv[hb + 1], 0.f),
            fmaxf(acc[2] + biasv[hb + 2], 0.f), fmaxf(acc[3] + biasv[hb + 3], 0.f));
  }
  __syncthreads();  // B1

  f16x8 hfrag[2];
#pragma unroll
  for (int ks = 0; ks < 2; ++ks)
    hfrag[ks] = frag_ldh(hlds, nloc, ks * 32 + quad * 8);

  _Float16* outs[3] = {vh, kh, qh};
#pragma unroll
  for (int p = 0; p < 3; ++p) {
    const _Float16* W = wlds + (p + 1) * 4608;
#pragma unroll
    for (int t = 0; t < 4; ++t) {
      f32x4 acc = {0.f, 0.f, 0.f, 0.f};
#pragma unroll
      for (int ks = 0; ks < 2; ++ks) {
        const f16x8 af = frag_ldh(W, t * 16 + l15, ks * 32 + quad * 8);
        acc = __builtin_amdgcn_mfma_f32_16x16x32_f16(af, hfrag[ks], acc, 0, 0, 0);
      }
      if (gn < NN) {
        *(f16x4*)(outs[p] + (size_t)gn * 64 + t * 16 + quad * 4) =
            pk4(acc[0], acc[1], acc[2], acc[3]);
      }
    }
  }
}

// ---------------------------------------------------------------------------
// Kernel B: MFMA (f16) edge pass, 4 barriers. Wave w owns edges [w*16,w*16+16).
// ---------------------------------------------------------------------------
__global__ __launch_bounds__(256, 4) void edge_pass(
    const int2* __restrict__ srt, const float* __restrict__ pos,
    const _Float16* __restrict__ vh, const _Float16* __restrict__ kh,
    const _Float16* __restrict__ qh, const _Float16* __restrict__ w16,
    const float* __restrict__ att_b1, const float* __restrict__ att_b2,
    const float* __restrict__ pos_w1, const float* __restrict__ pos_b1,
    const float* __restrict__ pos_b2, float* __restrict__ num,
    float* __restrict__ den) {
  __shared__ __align__(16) _Float16 smem[18432];
  __shared__ __align__(16) float posw1T[3 * 64];
  __shared__ float b1s[64], b2s[64], pb1s[64], pb2s[64];
  __shared__ int dsts[64];

  _Float16* W1  = smem;
  _Float16* W2  = smem + 4608;
  _Float16* PW2 = smem + 9216;
  _Float16* h1  = smem + 13824;
  float2* pairb = (float2*)smem;  // (msg, ex) interleaved

  const int tid = threadIdx.x;
  const int eb = blockIdx.x * 64;
  const int l15 = tid & 15;
  const int quad = (tid >> 4) & 3;
  const int wband = tid >> 6;
  const int eloc = wband * 16 + l15;

  // ---- phase 0a: per-lane edge read + B-frag: ad = q[dst]-k[src] (f16)
  int s_mine, d_mine;
  f16x8 bfrag[2];
  float dp0, dp1, dp2;
  {
    const int e = eb + eloc;
    int2 sd = make_int2(0, 0);
    int valid_d = -1;
    if (e < ET) {
      sd = srt[e];
      valid_d = sd.y;
    }
    s_mine = sd.x;
    d_mine = sd.y;
    if (quad == 0) dsts[eloc] = valid_d;
#pragma unroll
    for (int ks = 0; ks < 2; ++ks) {
      const f16x8 qv =
          *(const f16x8*)(qh + (size_t)d_mine * 64 + ks * 32 + quad * 8);
      const f16x8 kv =
          *(const f16x8*)(kh + (size_t)s_mine * 64 + ks * 32 + quad * 8);
      bfrag[ks] = qv - kv;
    }
    dp0 = pos[(size_t)d_mine * 3 + 0] - pos[(size_t)s_mine * 3 + 0];
    dp1 = pos[(size_t)d_mine * 3 + 1] - pos[(size_t)s_mine * 3 + 1];
    dp2 = pos[(size_t)d_mine * 3 + 2] - pos[(size_t)s_mine * 3 + 2];
  }

  // ---- phase 0b: stage pre-converted f16 weights (att_w1=4, att_w2=5, pos_w2=6)
  stage_w(W1, w16 + 4 * 4096, tid);
  stage_w(W2, w16 + 5 * 4096, tid);
  stage_w(PW2, w16 + 6 * 4096, tid);
  if (tid < 64) {
    b1s[tid] = att_b1[tid];
    b2s[tid] = att_b2[tid];
    pb1s[tid] = pos_b1[tid];
    pb2s[tid] = pos_b2[tid];
    posw1T[0 * 64 + tid] = pos_w1[tid * 3 + 0];
    posw1T[1 * 64 + tid] = pos_w1[tid * 3 + 1];
    posw1T[2 * 64 + tid] = pos_w1[tid * 3 + 2];
  }
  __syncthreads();  // B0

  // ---- GEMM1: h1 = relu(W1 . ad^T + b1) -> h1 rows [e][h] f16
#pragma unroll
  for (int t = 0; t < 4; ++t) {
    f32x4 acc = {0.f, 0.f, 0.f, 0.f};
#pragma unroll
    for (int ks = 0; ks < 2; ++ks) {
      const f16x8 af = frag_ldh(W1, t * 16 + l15, ks * 32 + quad * 8);
      acc = __builtin_amdgcn_mfma_f32_16x16x32_f16(af, bfrag[ks], acc, 0, 0, 0);
    }
    const int hb = t * 16 + quad * 4;
    *(f16x4*)(h1 + eloc * 72 + hb) =
        pk4(fmaxf(acc[0] + b1s[hb + 0], 0.f), fmaxf(acc[1] + b1s[hb + 1], 0.f),
            fmaxf(acc[2] + b1s[hb + 2], 0.f), fmaxf(acc[3] + b1s[hb + 3], 0.f));
  }

  // ---- hp in registers (k=3 pos-MLP layer 1 for this lane's 16 k-values)
  f16x8 hpfrag[2];
#pragma unroll
  for (int ks = 0; ks < 2; ++ks) {
    float hv[8];
#pragma unroll
    for (int j = 0; j < 8; ++j) {
      const int i = ks * 32 + quad * 8 + j;
      float a = pb1s[i];
      a = fmaf(dp0, posw1T[i], a);
      a = fmaf(dp1, posw1T[64 + i], a);
      a = fmaf(dp2, posw1T[128 + i], a);
      hv[j] = fmaxf(a, 0.f);
    }
    hpfrag[ks] = pk8(hv);
  }
  __syncthreads();  // B1: h1 visible

  // ---- GEMM2: alpha = relu(W2 . h1^T + b2); ex = exp(alpha)
  float ex[16], del[16];
  {
    f16x8 hfrag[2];
#pragma unroll
    for (int ks = 0; ks < 2; ++ks)
      hfrag[ks] = frag_ldh(h1, eloc, ks * 32 + quad * 8);
#pragma unroll
    for (int t = 0; t < 4; ++t) {
      f32x4 acc = {0.f, 0.f, 0.f, 0.f};
#pragma unroll
      for (int ks = 0; ks < 2; ++ks) {
        const f16x8 af = frag_ldh(W2, t * 16 + l15, ks * 32 + quad * 8);
        acc = __builtin_amdgcn_mfma_f32_16x16x32_f16(af, hfrag[ks], acc, 0, 0, 0);
      }
      const int ob = t * 16 + quad * 4;
#pragma unroll
      for (int r = 0; r < 4; ++r)
        ex[t * 4 + r] = __expf(fmaxf(acc[r] + b2s[ob + r], 0.f));
    }
  }
  // ---- GEMM3: delta = relu(PW2 . hp^T + pb2)
#pragma unroll
  for (int t = 0; t < 4; ++t) {
    f32x4 acc = {0.f, 0.f, 0.f, 0.f};
#pragma unroll
    for (int ks = 0; ks < 2; ++ks) {
      const f16x8 af = frag_ldh(PW2, t * 16 + l15, ks * 32 + quad * 8);
      acc = __builtin_amdgcn_mfma_f32_16x16x32_f16(af, hpfrag[ks], acc, 0, 0, 0);
    }
    const int ob = t * 16 + quad * 4;
#pragma unroll
    for (int r = 0; r < 4; ++r)
      del[t * 4 + r] = fmaxf(acc[r] + pb2s[ob + r], 0.f);
  }
  // v gather (f16, 8B per chunk)
  float vr[16];
#pragma unroll
  for (int t = 0; t < 4; ++t) {
    const f16x4 v4 = *(const f16x4*)(vh + (size_t)s_mine * 64 + t * 16 + quad * 4);
    vr[t * 4 + 0] = (float)v4[0];
    vr[t * 4 + 1] = (float)v4[1];
    vr[t * 4 + 2] = (float)v4[2];
    vr[t * 4 + 3] = (float)v4[3];
  }
  __syncthreads();  // B2: all smem MFMA reads done -> alias region free

  // ---- phase 5: (msg, ex) -> pairb, slot = (e + 2o) & 63
#pragma unroll
  for (int t = 0; t < 4; ++t) {
#pragma unroll
    for (int r = 0; r < 4; ++r) {
      const int o = t * 16 + quad * 4 + r;
      const int sl = (eloc + 2 * o) & 63;
      const float e_ = ex[t * 4 + r];
      pairb[o * 65 + sl] = make_float2(e_ * (vr[t * 4 + r] + del[t * 4 + r]), e_);
    }
  }
  __syncthreads();  // B3

  // ---- phase 6: segmented reduce over sorted-dst runs, then atomics
  {
    const int c = tid & 63;
    const int r = tid >> 6;
    float am = 0.f, ae = 0.f;
    int cur = -1;
#pragma unroll 1
    for (int t2 = 0; t2 < 16; ++t2) {
      const int el = r * 16 + t2;
      const int d = dsts[el];
      if (d != cur) {
        if (cur >= 0) {
          unsafeAtomicAdd(num + (size_t)cur * 64 + c, am);
          unsafeAtomicAdd(den + (size_t)cur * 64 + c, ae);
        }
        cur = d;
        am = 0.f;
        ae = 0.f;
      }
      if (d >= 0) {
        const float2 pe = pairb[c * 65 + ((el + 2 * c) & 63)];
        am += pe.x;
        ae += pe.y;
      }
    }
    if (cur >= 0) {
      unsafeAtomicAdd(num + (size_t)cur * 64 + c, am);
      unsafeAtomicAdd(den + (size_t)cur * 64 + c, ae);
    }
  }
}

// ---------------------------------------------------------------------------
// Kernel C: out = relu((num/(den+1e-16)) @ W_out.T + b_out), MFMA f16.
// ---------------------------------------------------------------------------
__global__ __launch_bounds__(256, 4) void out_proj(
    const float* __restrict__ num, const float* __restrict__ den,
    const _Float16* __restrict__ w16, const float* __restrict__ b_out,
    float* __restrict__ out) {
  __shared__ __align__(16) _Float16 wlds[4608];
  __shared__ float biasv[64];

  const int tid = threadIdx.x;
  const int nb = blockIdx.x * 64;
  const int l15 = tid & 15;
  const int quad = (tid >> 4) & 3;
  const int wband = tid >> 6;
  const int gn = nb + wband * 16 + l15;

  stage_w(wlds, w16 + 7 * 4096, tid);
  if (tid < 64) biasv[tid] = b_out[tid];

  f16x8 bfrag[2];
#pragma unroll
  for (int ks = 0; ks < 2; ++ks) {
    float y[8] = {0.f, 0.f, 0.f, 0.f, 0.f, 0.f, 0.f, 0.f};
    if (gn < NN) {
      const size_t base = (size_t)gn * 64 + ks * 32 + quad * 8;
      const float4 n0 = *(const float4*)(num + base);
      const float4 n1 = *(const float4*)(num + base + 4);
      const float4 d0 = *(const float4*)(den + base);
      const float4 d1 = *(const float4*)(den + base + 4);
      y[0] = n0.x / (d0.x + 1e-16f); y[1] = n0.y / (d0.y + 1e-16f);
      y[2] = n0.z / (d0.z + 1e-16f); y[3] = n0.w / (d0.w + 1e-16f);
      y[4] = n1.x / (d1.x + 1e-16f); y[5] = n1.y / (d1.y + 1e-16f);
      y[6] = n1.z / (d1.z + 1e-16f); y[7] = n1.w / (d1.w + 1e-16f);
    }
    bfrag[ks] = pk8(y);
  }
  __syncthreads();

#pragma unroll
  for (int t = 0; t < 4; ++t) {
    f32x4 acc = {0.f, 0.f, 0.f, 0.f};
#pragma unroll
    for (int ks = 0; ks < 2; ++ks) {
      const f16x8 af = frag_ldh(wlds, t * 16 + l15, ks * 32 + quad * 8);
      acc = __builtin_amdgcn_mfma_f32_16x16x32_f16(af, bfrag[ks], acc, 0, 0, 0);
    }
    if (gn < NN) {
      const int ob = t * 16 + quad * 4;
      float4 r;
      r.x = fmaxf(acc[0] + biasv[ob + 0], 0.f);
      r.y = fmaxf(acc[1] + biasv[ob + 1], 0.f);
      r.z = fmaxf(acc[2] + biasv[ob + 2], 0.f);
      r.w = fmaxf(acc[3] + biasv[ob + 3], 0.f);
      *(float4*)(out + (size_t)gn * 64 + ob) = r;
    }
  }
}

extern "C" void kernel_launch(void* const* d_in, const int* in_sizes, int n_in,
                              void* d_out, int out_size, void* d_ws,
                              size_t ws_size, hipStream_t stream) {
  const float* x      = (const float*)d_in[0];
  const float* pos    = (const float*)d_in[1];
  const int*   ei     = (const int*)d_in[2];
  const float* W_in   = (const float*)d_in[3];
  const float* b_in   = (const float*)d_in[4];
  const float* W_out  = (const float*)d_in[5];
  const float* b_out  = (const float*)d_in[6];
  const float* W_lin  = (const float*)d_in[7];
  const float* W_src  = (const float*)d_in[8];
  const float* W_dst  = (const float*)d_in[9];
  const float* pos_w1 = (const float*)d_in[10];
  const float* pos_b1 = (const float*)d_in[11];
  const float* pos_w2 = (const float*)d_in[12];
  const float* pos_b2 = (const float*)d_in[13];
  const float* att_w1 = (const float*)d_in[14];
  const float* att_b1 = (const float*)d_in[15];
  const float* att_w2 = (const float*)d_in[16];
  const float* att_b2 = (const float*)d_in[17];

  float* ws = (float*)d_ws;
  const size_t NC = (size_t)NN * C;
  float* num = ws;                       // NC f32
  float* den = ws + NC;                  // NC f32
  _Float16* vh = (_Float16*)(ws + 2 * NC);  // NC f16
  _Float16* kh = vh + NC;                    // NC f16
  _Float16* qh = kh + NC;                    // NC f16
  _Float16* w16 = qh + NC;                   // 8*4096 f16
  int* ib     = (int*)(w16 + 8 * 4096);
  int* cnt2   = ib;                      // 8*NN
  int* curs2  = ib + 8 * NN;             // 8*NN
  int* bsum   = ib + 16 * NN;            // NBLK
  int2* srt   = (int2*)(((uintptr_t)(bsum + NBLK) + 15) & ~(uintptr_t)15);

  const dim3 blk(256);
  prep_kernel<<<dim3(8), blk, 0, stream>>>(W_in, W_lin, W_src, W_dst, att_w1,
                                           att_w2, pos_w2, W_out, w16, cnt2);
  node_proj<<<dim3((NN + 63) / 64), blk, 0, stream>>>(x, b_in, w16, ei, cnt2,
                                                      vh, kh, qh);
  scan_partial<<<dim3(NBLK + ZBLK), blk, 0, stream>>>(cnt2, bsum, num);
  scan_final<<<dim3(NBLK), blk, 0, stream>>>(cnt2, bsum, curs2);
  scatter_kernel<<<dim3(NCHUNK), blk, 0, stream>>>(ei, curs2, srt);
  edge_pass<<<dim3((ET + 63) / 64), blk, 0, stream>>>(
      srt, pos, vh, kh, qh, w16, att_b1, att_b2, pos_w1, pos_b1, pos_b2, num,
      den);
  out_proj<<<dim3((NN + 63) / 64), blk, 0, stream>>>(num, den, w16, b_out,
                                                     (float*)d_out);
}